// Round 4
// baseline (12972.658 us; speedup 1.0000x reference)
//
#include <hip/hip_runtime.h>
#include <math.h>

static constexpr int BATCH = 64;
static constexpr int NR  = 512;    // rows per matrix (n)
static constexpr int ND  = 384;    // feature dim (N)
static constexpr int RK  = 24;     // rank
static constexpr int NSI = 5;      // Newton-Schulz iters (whitening)
static constexpr int POLAR_ITERS = 36;
static constexpr int PNB = 64;     // tridiag panel width
static constexpr long SZC = (long)BATCH * ND * ND;      // 9,437,184 floats
static constexpr int SSTR = BATCH * RK;                 // 1536 (inverse-iter solve stride)

#define MODE_PLAIN 0
#define MODE_COV   1
#define MODE_NST   2
#define MODE_SCALE 3
#define MODE_ACC   4

// ---------------- generic batched tiled SGEMM (128x128 tile, 8x8 microtile) ----
template<int TA>
__global__ __launch_bounds__(256)
void gemm_kernel(const float* __restrict__ Ag, const float* __restrict__ Bg,
                 float* __restrict__ Cg, int M, int N, int K,
                 long sA, long sB, long sC, int lda, int ldb, int ldc,
                 int mode, const float* __restrict__ scale)
{
    const int batch = blockIdx.y;
    const int tilesN = N >> 7;            // N/128
    const int tx = blockIdx.x % tilesN;
    const int ty = blockIdx.x / tilesN;
    const int n0 = tx * 128, m0 = ty * 128;
    const float* A = Ag + (long)batch * sA;
    const float* Bm = Bg + (long)batch * sB;
    float* C = Cg + (long)batch * sC;

    __shared__ float As[16][132];
    __shared__ float Bs[16][132];

    const int tid = threadIdx.x;
    const int tr = tid >> 4, tc = tid & 15;   // 16x16 thread grid

    float acc[8][8];
#pragma unroll
    for (int i = 0; i < 8; i++)
#pragma unroll
        for (int j = 0; j < 8; j++) acc[i][j] = 0.f;

    for (int k0 = 0; k0 < K; k0 += 16) {
        if (TA) {
#pragma unroll
            for (int q = 0; q < 2; q++) {
                int idx = tid + q * 256;
                int kk = idx >> 5, mq = (idx & 31) * 4;
                float4 av = *(const float4*)&A[(long)(k0 + kk) * lda + m0 + mq];
                *(float4*)&As[kk][mq] = av;
            }
        } else {
#pragma unroll
            for (int q = 0; q < 2; q++) {
                int idx = tid + q * 256;
                int mrow = idx >> 2, kq = (idx & 3) * 4;
                float4 av = *(const float4*)&A[(long)(m0 + mrow) * lda + k0 + kq];
                As[kq + 0][mrow] = av.x;
                As[kq + 1][mrow] = av.y;
                As[kq + 2][mrow] = av.z;
                As[kq + 3][mrow] = av.w;
            }
        }
#pragma unroll
        for (int q = 0; q < 2; q++) {
            int idx = tid + q * 256;
            int kk = idx >> 5, nq = (idx & 31) * 4;
            float4 bv = *(const float4*)&Bm[(long)(k0 + kk) * ldb + n0 + nq];
            *(float4*)&Bs[kk][nq] = bv;
        }
        __syncthreads();

#pragma unroll
        for (int kk = 0; kk < 16; kk++) {
            float4 a0 = *(const float4*)&As[kk][tr * 4];
            float4 a1 = *(const float4*)&As[kk][tr * 4 + 64];
            float4 b0 = *(const float4*)&Bs[kk][tc * 4];
            float4 b1 = *(const float4*)&Bs[kk][tc * 4 + 64];
            float av[8] = {a0.x, a0.y, a0.z, a0.w, a1.x, a1.y, a1.z, a1.w};
            float bv[8] = {b0.x, b0.y, b0.z, b0.w, b1.x, b1.y, b1.z, b1.w};
#pragma unroll
            for (int i = 0; i < 8; i++)
#pragma unroll
                for (int j = 0; j < 8; j++) acc[i][j] += av[i] * bv[j];
        }
        __syncthreads();
    }

    float scl = 1.f;
    if (mode == MODE_SCALE) scl = 1.0f / sqrtf(scale[batch]);

#pragma unroll
    for (int ih = 0; ih < 2; ih++) {
#pragma unroll
        for (int ii = 0; ii < 4; ii++) {
            int gm = m0 + ih * 64 + tr * 4 + ii;
#pragma unroll
            for (int jh = 0; jh < 2; jh++) {
                int gn0 = n0 + jh * 64 + tc * 4;
                float* crow = C + (long)gm * ldc + gn0;
                float4 old;
                if (mode == MODE_ACC) old = *(const float4*)crow;
                float vout[4];
#pragma unroll
                for (int jj = 0; jj < 4; jj++) {
                    int gn = gn0 + jj;
                    float v = acc[ih * 4 + ii][jh * 4 + jj];
                    if (mode == MODE_COV)      v = v * (1.0f / 512.0f) + ((gm == gn) ? 1e-5f : 0.f);
                    else if (mode == MODE_NST) v = ((gm == gn) ? 1.5f : 0.f) - 0.5f * v;
                    else if (mode == MODE_SCALE) v *= scl;
                    vout[jj] = v;
                }
                if (mode == MODE_ACC) {
                    vout[0] += old.x; vout[1] += old.y; vout[2] += old.z; vout[3] += old.w;
                }
                float4 st = {vout[0], vout[1], vout[2], vout[3]};
                *(float4*)crow = st;
            }
        }
    }
}

// ---------------- Frobenius norm per batch ----------------
__global__ __launch_bounds__(256)
void frob_kernel(const float* __restrict__ Cm, float* __restrict__ nrm)
{
    int b = blockIdx.x;
    const float* p = Cm + (long)b * ND * ND;
    float s = 0.f;
    for (int i = threadIdx.x; i < ND * ND; i += 256) { float v = p[i]; s += v * v; }
    __shared__ float red[256];
    red[threadIdx.x] = s; __syncthreads();
    for (int off = 128; off > 0; off >>= 1) {
        if (threadIdx.x < off) red[threadIdx.x] += red[threadIdx.x + off];
        __syncthreads();
    }
    if (threadIdx.x == 0) nrm[b] = sqrtf(red[0]);
}

// ---------------- Y0 = C/normC (in place), Z0 = I ----------------
__global__ __launch_bounds__(256)
void init_kernel(float* __restrict__ Y, float* __restrict__ Z, const float* __restrict__ nrm)
{
    const int total = BATCH * ND * ND;
    for (int idx = blockIdx.x * 256 + threadIdx.x; idx < total; idx += gridDim.x * 256) {
        int b = idx / (ND * ND);
        int rem = idx - b * (ND * ND);
        int r = rem / ND, c = rem - r * ND;
        Y[idx] = Y[idx] / nrm[b];
        Z[idx] = (r == c) ? 1.f : 0.f;
    }
}

// ---------------- block reduction over 768 threads ----------------
__device__ __forceinline__ float bred768(float v, float* red12, int t)
{
#pragma unroll
    for (int off = 32; off > 0; off >>= 1) v += __shfl_down(v, off);
    if ((t & 63) == 0) red12[t >> 6] = v;
    __syncthreads();
    float r = 0.f;
#pragma unroll
    for (int i = 0; i < 12; i++) r += red12[i];
    __syncthreads();
    return r;
}

// ---------------- Blocked Householder tridiagonalization: panel kernel ----------
// One WG (768 threads) per batch. Within a panel of PNB columns the trailing
// matrix is NOT written; A_eff = A - U W^T - W U^T is maintained implicitly.
// U lives in A's processed rows (row k holds u_k, coalesced); W in Wg[PNB][ND].
// Trailing updates are applied once per panel by syr2k_update (full device).
__global__ __launch_bounds__(768)
void tridiag_panel(float* __restrict__ Gall, float* __restrict__ dA,
                   float* __restrict__ eA, float* __restrict__ tauA,
                   float* __restrict__ Wgall, int k0)
{
    int b = blockIdx.x;
    float* A = Gall + (long)b * ND * ND;
    float* Wg = Wgall + (long)b * (PNB * ND);
    float* d = dA + b * ND; float* e = eA + b * ND; float* tau = tauA + b * ND;
    const int t = threadIdx.x;
    const int h = (t >= ND) ? 1 : 0;
    const int c = t - h * ND;            // 0..383
    __shared__ float u_s[ND];
    __shared__ float pp[2][ND];
    __shared__ float ukv[PNB], wkv[PNB], al[PNB], be[PNB];
    __shared__ float red12[12];
    __shared__ float s_tau;

    const int jcnt = min(PNB, ND - 2 - k0);

    for (int j = 0; j < jcnt; j++) {
        const int k = k0 + j;
        const int m = ND - 1 - k;
        // scalars u_l[k], w_l[k] for row-k extraction & diagonal correction
        if (t < j) { ukv[t] = A[(long)(k0 + t) * ND + k]; wkv[t] = Wg[t * ND + k]; }
        __syncthreads();
        // x = (row k of A_eff), trailing part
        float x = 0.f;
        if (!h && c < m) {
            x = A[(long)k * ND + (k + 1) + c];
            for (int l = 0; l < j; l++) {
                x -= ukv[l] * Wg[l * ND + (k + 1) + c]
                   + wkv[l] * A[(long)(k0 + l) * ND + (k + 1) + c];
            }
            u_s[c] = x;
        }
        float sigma = bred768(x * x, red12, t);   // syncs inside; u_s visible after
        if (t == 0) {
            float v0 = u_s[0];
            float normx = sqrtf(sigma);
            float alpha = (v0 >= 0.f) ? -normx : normx;
            float denom = sigma - alpha * v0;
            float tk = (denom > 1e-30f) ? 1.f / denom : 0.f;   // tau = 2/||u||^2
            s_tau = tk;
            float diag = A[(long)k * ND + k];
            for (int l = 0; l < j; l++) diag -= 2.f * ukv[l] * wkv[l];
            e[k] = alpha; tau[k] = tk; d[k] = diag;
            u_s[0] = v0 - alpha;
        }
        __syncthreads();
        const float tk = s_tau;
        const int mh = m >> 1;
        const int i0 = h ? mh : 0;
        const int i1 = h ? m : mh;

        // A-matvec partial over the CLEAN stored trailing block (never written
        // during the panel -> L2-resident, no writeback pressure)
        float p = 0.f;
        if (c < m) {
            const float* col = A + (long)(k + 1) * ND + (k + 1) + c;
            int i = i0;
            for (; i + 4 <= i1; i += 4) {
                p += col[(long)(i    ) * ND] * u_s[i]
                   + col[(long)(i + 1) * ND] * u_s[i + 1]
                   + col[(long)(i + 2) * ND] * u_s[i + 2]
                   + col[(long)(i + 3) * ND] * u_s[i + 3];
            }
            for (; i < i1; i++) p += col[(long)i * ND] * u_s[i];
        }
        pp[h][c] = p;
        // wave-parallel dots: al[l] = w_l . u, be[l] = u_l . u
        {
            int wv = t >> 6, ln = t & 63;
            for (int l = wv; l < j; l += 12) {
                float sa = 0.f, sb = 0.f;
                const float* wrow = Wg + l * ND + (k + 1);
                const float* urow = A + (long)(k0 + l) * ND + (k + 1);
                for (int i = ln; i < m; i += 64) { sa += wrow[i] * u_s[i]; sb += urow[i] * u_s[i]; }
#pragma unroll
                for (int off = 32; off > 0; off >>= 1) {
                    sa += __shfl_down(sa, off); sb += __shfl_down(sb, off);
                }
                if (ln == 0) { al[l] = sa; be[l] = sb; }
            }
        }
        __syncthreads();
        // p_c = tau * (A u - U al - W be)_c
        float contrib = 0.f, pc = 0.f;
        if (!h && c < m) {
            pc = pp[0][c] + pp[1][c];
            for (int l = 0; l < j; l++) {
                pc -= al[l] * A[(long)(k0 + l) * ND + (k + 1) + c]
                    + be[l] * Wg[l * ND + (k + 1) + c];
            }
            pc *= tk;
            contrib = u_s[c] * pc;
        }
        float dotup = bred768(contrib, red12, t);
        float sc = 0.5f * tk * dotup;
        if (!h && c < m) {
            float w = pc - sc * u_s[c];
            Wg[j * ND + (k + 1) + c] = w;          // store w_j
            A[(long)k * ND + (k + 1) + c] = u_s[c]; // store reflector into row k
        }
        __syncthreads();
    }
    // last panel: finalize trailing 2x2 with pending low-rank corrections
    if (k0 + PNB >= ND - 2 && t == 0) {
        float d0 = A[(long)(ND - 2) * ND + (ND - 2)];
        float e0 = A[(long)(ND - 2) * ND + (ND - 1)];
        float d1 = A[(long)(ND - 1) * ND + (ND - 1)];
        for (int l = 0; l < jcnt; l++) {
            float u0 = A[(long)(k0 + l) * ND + (ND - 2)];
            float u1 = A[(long)(k0 + l) * ND + (ND - 1)];
            float w0 = Wg[l * ND + (ND - 2)];
            float w1 = Wg[l * ND + (ND - 1)];
            d0 -= 2.f * u0 * w0;
            e0 -= u0 * w1 + w0 * u1;
            d1 -= 2.f * u1 * w1;
        }
        d[ND - 2] = d0; d[ND - 1] = d1; e[ND - 2] = e0;
        e[ND - 1] = 0.f; tau[ND - 2] = 0.f; tau[ND - 1] = 0.f;
    }
}

// ---------------- trailing update: A -= U W^T + W U^T (full device) ----------
__global__ __launch_bounds__(256)
void syr2k_update(float* __restrict__ Gall, const float* __restrict__ Wgall, int k0)
{
    const int k1 = k0 + PNB;
    const int tiles = (ND - k1) >> 6;    // trailing size is a multiple of 64
    int b = blockIdx.y;
    int ti = blockIdx.x / tiles, tj = blockIdx.x % tiles;
    int i0 = k1 + ti * 64, c0 = k1 + tj * 64;
    float* A = Gall + (long)b * ND * ND;
    const float* Wg = Wgall + (long)b * (PNB * ND);

    __shared__ float Us[PNB][65], Ws[PNB][65], Uc[PNB][65], Wc[PNB][65];
    int t = threadIdx.x;
    for (int q = t; q < PNB * 16; q += 256) {
        int l = q >> 4, c4 = (q & 15) * 4;
        *(float4*)&Us[l][c4] = *(const float4*)&A[(long)(k0 + l) * ND + i0 + c4];
        *(float4*)&Ws[l][c4] = *(const float4*)&Wg[l * ND + i0 + c4];
        *(float4*)&Uc[l][c4] = *(const float4*)&A[(long)(k0 + l) * ND + c0 + c4];
        *(float4*)&Wc[l][c4] = *(const float4*)&Wg[l * ND + c0 + c4];
    }
    __syncthreads();
    int tr = t >> 4, tc = t & 15;
    float acc[4][4];
#pragma unroll
    for (int a = 0; a < 4; a++)
#pragma unroll
        for (int q = 0; q < 4; q++) acc[a][q] = 0.f;
    for (int l = 0; l < PNB; l++) {
        float ua[4], wa[4], ub[4], wb[4];
#pragma unroll
        for (int a = 0; a < 4; a++) {
            ua[a] = Us[l][tr * 4 + a]; wa[a] = Ws[l][tr * 4 + a];
            ub[a] = Uc[l][tc * 4 + a]; wb[a] = Wc[l][tc * 4 + a];
        }
#pragma unroll
        for (int a = 0; a < 4; a++)
#pragma unroll
            for (int q = 0; q < 4; q++) acc[a][q] += ua[a] * wb[q] + wa[a] * ub[q];
    }
#pragma unroll
    for (int a = 0; a < 4; a++) {
        float* crow = &A[(long)(i0 + tr * 4 + a) * ND + c0 + tc * 4];
        float4 old = *(const float4*)crow;
        old.x -= acc[a][0]; old.y -= acc[a][1]; old.z -= acc[a][2]; old.w -= acc[a][3];
        *(float4*)crow = old;
    }
}

// ---------------- Sturm bisection: top-24 eigenvalues ----------------
__global__ __launch_bounds__(64)
void eigvals_kernel(const float* __restrict__ dA, const float* __restrict__ eA,
                    float* __restrict__ lamA)
{
    int b = blockIdx.x, t = threadIdx.x;   // 64 threads
    __shared__ float d[ND], e2[ND], ea[ND], red[64];
    for (int i = t; i < ND; i += 64) {
        d[i] = dA[b * ND + i];
        float ev = eA[b * ND + i];
        ea[i] = fabsf(ev); e2[i] = ev * ev;
    }
    __syncthreads();
    float lo = 1e30f, hi = -1e30f;
    for (int i = t; i < ND; i += 64) {
        float r = ea[i] + ((i > 0) ? ea[i - 1] : 0.f);
        lo = fminf(lo, d[i] - r); hi = fmaxf(hi, d[i] + r);
    }
    red[t] = lo; __syncthreads();
    for (int off = 32; off > 0; off >>= 1) {
        if (t < off) red[t] = fminf(red[t], red[t + off]);
        __syncthreads();
    }
    lo = red[0]; __syncthreads();
    red[t] = hi; __syncthreads();
    for (int off = 32; off > 0; off >>= 1) {
        if (t < off) red[t] = fmaxf(red[t], red[t + off]);
        __syncthreads();
    }
    hi = red[0];
    if (t < RK) {
        int idx = ND - 1 - t;          // ascending index (t=0 -> largest)
        float a = lo, c = hi;
        for (int it = 0; it < 42; it++) {
            float mid = 0.5f * (a + c);
            int cnt = 0;
            float q = d[0] - mid;
            if (q < 0.f) cnt++;
            for (int i = 1; i < ND; i++) {
                float den = q;
                if (fabsf(den) < 1e-25f) den = (den < 0.f) ? -1e-25f : 1e-25f;
                q = d[i] - mid - e2[i - 1] / den;
                if (q < 0.f) cnt++;
            }
            if (cnt > idx) c = mid; else a = mid;
        }
        lamA[b * RK + t] = 0.5f * (a + c);
    }
}

// ---------------- tridiagonal inverse iteration (pivoted LU) ----------------
__global__ __launch_bounds__(64)
void invit_kernel(const float* __restrict__ dA, const float* __restrict__ eA,
                  const float* __restrict__ lamA, float* __restrict__ scr)
{
    int b = blockIdx.x, t = threadIdx.x;
    __shared__ float d[ND], e[ND];
    for (int i = t; i < ND; i += 64) { d[i] = dA[b * ND + i]; e[i] = eA[b * ND + i]; }
    __syncthreads();
    if (t >= RK) return;
    const int s = b * RK + t;
    float* ua = scr;
    float* ub = scr + (long)ND * SSTR;
    float* uc = scr + 2L * ND * SSTR;
    float* ul = scr + 3L * ND * SSTR;
    float* up = scr + 4L * ND * SSTR;
    float* y  = scr + 5L * ND * SSTR;
    float lam = lamA[s];
    float ai = d[0] - lam;
    float bc = e[0];
    for (int i = 0; i < ND - 1; i++) {
        float sub = e[i];
        float dn = d[i + 1] - lam;
        float en = (i + 1 < ND - 1) ? e[i + 1] : 0.f;
        long o = (long)i * SSTR + s;
        if (fabsf(ai) >= fabsf(sub)) {
            float aa = (ai == 0.f) ? 1e-20f : ai;
            float mlt = sub / aa;
            ua[o] = aa; ub[o] = bc; uc[o] = 0.f; ul[o] = mlt; up[o] = 0.f;
            ai = dn - mlt * bc;
            bc = en;
        } else {
            float mlt = ai / sub;
            ua[o] = sub; ub[o] = dn; uc[o] = en; ul[o] = mlt; up[o] = 1.f;
            ai = bc - mlt * dn;
            bc = -mlt * en;
        }
    }
    { long o = (long)(ND - 1) * SSTR + s; ua[o] = (ai == 0.f) ? 1e-20f : ai; ub[o] = 0.f; uc[o] = 0.f; }

    for (int pass = 0; pass < 2; pass++) {
        if (pass == 0) {
            for (int i = 0; i < ND; i++) {
                unsigned h = ((unsigned)i * 1103515245u) ^ ((unsigned)s * 747796405u);
                h *= 2654435769u; h ^= h >> 16;
                y[(long)i * SSTR + s] = ((float)(h & 0xFFFFu) * (1.f / 65536.f)) - 0.5f;
            }
        }
        for (int i = 0; i < ND - 1; i++) {
            long o = (long)i * SSTR + s, o1 = o + SSTR;
            float yi = y[o], y1 = y[o1];
            if (up[o] == 0.f) { y[o1] = y1 - ul[o] * yi; }
            else { y[o] = y1; y[o1] = yi - ul[o] * y1; }
        }
        {
            long oN = (long)(ND - 1) * SSTR + s;
            float xN = y[oN] / ua[oN]; y[oN] = xN;
            long o = oN - SSTR;
            float x1 = xN, x2 = 0.f;
            float xm = (y[o] - ub[o] * x1) / ua[o]; y[o] = xm; x2 = x1; x1 = xm;
            for (int i = ND - 3; i >= 0; i--) {
                o -= SSTR;
                float xi = (y[o] - ub[o] * x1 - uc[o] * x2) / ua[o];
                y[o] = xi; x2 = x1; x1 = xi;
            }
        }
        float nn = 0.f;
        for (int i = 0; i < ND; i++) { float v = y[(long)i * SSTR + s]; nn += v * v; }
        float inv = (nn > 0.f) ? 1.f / sqrtf(nn) : 0.f;
        for (int i = 0; i < ND; i++) y[(long)i * SSTR + s] *= inv;
    }
}

// ---------------- MGS + Householder back-transform (one WG per batch) ----------------
__device__ __forceinline__ float blockSum384(float v, float* red6, int t)
{
#pragma unroll
    for (int off = 32; off > 0; off >>= 1) v += __shfl_down(v, off);
    __syncthreads();
    if ((t & 63) == 0) red6[t >> 6] = v;
    __syncthreads();
    return red6[0] + red6[1] + red6[2] + red6[3] + red6[4] + red6[5];
}

__global__ __launch_bounds__(384)
void orthbt_kernel(const float* __restrict__ xx, const float* __restrict__ Gall,
                   const float* __restrict__ tauA, float* __restrict__ Qout)
{
    int b = blockIdx.x, t = threadIdx.x;   // 384 threads
    __shared__ float Y[ND][RK + 1];
    __shared__ float u[ND];
    __shared__ float red[ND];
    __shared__ float red6[8];
    __shared__ float sarr[RK];

    for (int j = 0; j < RK; j++) Y[t][j] = xx[(long)t * SSTR + b * RK + j];
    __syncthreads();

    for (int j = 0; j < RK; j++) {
        float nv = blockSum384(Y[t][j] * Y[t][j], red6, t);
        float inv = (nv > 1e-30f) ? 1.f / sqrtf(nv) : 0.f;
        Y[t][j] *= inv;
        for (int l = j + 1; l < RK; l++) {
            float dt = blockSum384(Y[t][j] * Y[t][l], red6, t);
            Y[t][l] -= dt * Y[t][j];
        }
    }
    __syncthreads();

    const float* A = Gall + (long)b * ND * ND;
    const float* tau = tauA + b * ND;
    const int col = t % RK;       // 384 = 16*24
    const int sl = t / RK;
    for (int k = ND - 3; k >= 0; k--) {
        int m = ND - 1 - k;
        for (int i = t; i < m; i += 384) u[i] = A[(long)k * ND + (k + 1 + i)];
        float tk = tau[k];
        __syncthreads();
        float p = 0.f;
        for (int i = sl; i < m; i += 16) p += u[i] * Y[k + 1 + i][col];
        red[col * 16 + sl] = p; __syncthreads();
        if (sl == 0) {
            float ssum = 0.f;
            for (int q = 0; q < 16; q++) ssum += red[col * 16 + q];
            sarr[col] = tk * ssum;
        }
        __syncthreads();
        float sv = sarr[col];
        for (int i = sl; i < m; i += 16) Y[k + 1 + i][col] -= u[i] * sv;
        __syncthreads();
    }
    for (int l = t; l < ND * RK; l += 384) {
        int i = l / RK, j = l - i * RK;
        Qout[(long)b * ND * RK + l] = Y[i][j];
    }
}

// ---------------- Sp = X_w @ Q ----------------
__global__ __launch_bounds__(256)
void proj_kernel(const float* __restrict__ Xw, const float* __restrict__ Qall,
                 float* __restrict__ P)
{
    int b = blockIdx.y;
    int r0 = blockIdx.x * 256;
    __shared__ float Qs[ND][RK + 1];
    const float* Q = Qall + (long)b * ND * RK;
    for (int l = threadIdx.x; l < ND * RK; l += 256) {
        int i = l / RK, j = l - i * RK;
        Qs[i][j] = Q[l];
    }
    __syncthreads();
    int r = r0 + threadIdx.x;
    const float* X = Xw + (long)b * NR * ND + (long)r * ND;
    float acc[RK];
#pragma unroll
    for (int j = 0; j < RK; j++) acc[j] = 0.f;
    for (int k = 0; k < ND; k++) {
        float xv = X[k];
#pragma unroll
        for (int j = 0; j < RK; j++) acc[j] += xv * Qs[k][j];
    }
    float* Pr = P + (long)b * NR * RK + (long)r * RK;
#pragma unroll
    for (int j = 0; j < RK; j++) Pr[j] = acc[j];
}

// ---------------- M = Sp^T Tp ; R = polar(M) via Newton-Schulz ; write R - I ----------------
__global__ __launch_bounds__(256)
void polar_kernel(const float* __restrict__ Sp, const float* __restrict__ Tp,
                  float* __restrict__ RmI)
{
    int b = blockIdx.x, t = threadIdx.x;
    __shared__ float Sb[128][RK + 1], Tb[128][RK + 1];
    __shared__ float Xm[RK][RK + 1], Bm[RK][RK + 1], Mm[RK][RK + 1];
    __shared__ float red[256];

    float accM[3] = {0.f, 0.f, 0.f};
    for (int c = 0; c < 4; c++) {
        for (int l = t; l < 128 * RK; l += 256) {
            int row = l / RK, colj = l - row * RK;
            Sb[row][colj] = Sp[(long)b * NR * RK + (long)(c * 128 + row) * RK + colj];
            Tb[row][colj] = Tp[(long)b * NR * RK + (long)(c * 128 + row) * RK + colj];
        }
        __syncthreads();
        for (int q = 0; q < 3; q++) {
            int e = t + q * 256;
            if (e < RK * RK) {
                int r = e / RK, s2 = e - r * RK;
                float a = 0.f;
                for (int n = 0; n < 128; n++) a += Sb[n][r] * Tb[n][s2];
                accM[q] += a;
            }
        }
        __syncthreads();
    }
    float ss = 0.f;
    for (int q = 0; q < 3; q++) {
        int e = t + q * 256;
        if (e < RK * RK) {
            int r = e / RK, s2 = e - r * RK;
            Mm[r][s2] = accM[q];
            ss += accM[q] * accM[q];
        }
    }
    red[t] = ss; __syncthreads();
    for (int off = 128; off > 0; off >>= 1) {
        if (t < off) red[t] += red[t + off];
        __syncthreads();
    }
    float fro = sqrtf(red[0]);
    float inv = (fro > 1e-30f) ? 1.f / fro : 0.f;
    for (int q = 0; q < 3; q++) {
        int e = t + q * 256;
        if (e < RK * RK) { int r = e / RK, s2 = e - r * RK; Xm[r][s2] = Mm[r][s2] * inv; }
    }
    __syncthreads();
    for (int it = 0; it < POLAR_ITERS; it++) {
        for (int q = 0; q < 3; q++) {
            int e = t + q * 256;
            if (e < RK * RK) {
                int r = e / RK, s2 = e - r * RK;
                float a = 0.f;
                for (int k = 0; k < RK; k++) a += Xm[k][r] * Xm[k][s2];
                Bm[r][s2] = a;
            }
        }
        __syncthreads();
        for (int q = 0; q < 3; q++) {
            int e = t + q * 256;
            if (e < RK * RK) {
                int r = e / RK, s2 = e - r * RK;
                float a = 0.f;
                for (int k = 0; k < RK; k++) a += Xm[r][k] * Bm[k][s2];
                Mm[r][s2] = 1.5f * Xm[r][s2] - 0.5f * a;
            }
        }
        __syncthreads();
        for (int q = 0; q < 3; q++) {
            int e = t + q * 256;
            if (e < RK * RK) { int r = e / RK, s2 = e - r * RK; Xm[r][s2] = Mm[r][s2]; }
        }
        __syncthreads();
    }
    for (int q = 0; q < 3; q++) {
        int e = t + q * 256;
        if (e < RK * RK) {
            int r = e / RK, s2 = e - r * RK;
            RmI[(long)b * RK * RK + e] = Xm[r][s2] - ((r == s2) ? 1.f : 0.f);
        }
    }
}

// ---------------- aligned = S_w + Sp (R-I) Q^T  (writes d_out) ----------------
__global__ __launch_bounds__(256)
void align_kernel(const float* __restrict__ Sw, const float* __restrict__ Sp,
                  const float* __restrict__ RmI, const float* __restrict__ Qall,
                  float* __restrict__ out)
{
    int b = blockIdx.y;
    int r0 = blockIdx.x * 64;
    int t = threadIdx.x;
    __shared__ float Qs[ND][RK + 1];
    __shared__ float Rm[RK][RK + 1];
    __shared__ float Ss[64][RK + 1];
    __shared__ float W[64][RK + 1];

    for (int l = t; l < ND * RK; l += 256) {
        int i = l / RK, j = l - i * RK;
        Qs[i][j] = Qall[(long)b * ND * RK + l];
    }
    for (int l = t; l < RK * RK; l += 256) {
        int i = l / RK, j = l - i * RK;
        Rm[i][j] = RmI[(long)b * RK * RK + l];
    }
    for (int l = t; l < 64 * RK; l += 256) {
        int i = l / RK, j = l - i * RK;
        Ss[i][j] = Sp[(long)b * NR * RK + (long)(r0 + i) * RK + j];
    }
    __syncthreads();
    for (int l = t; l < 64 * RK; l += 256) {
        int r = l / RK, j = l - r * RK;
        float a = 0.f;
        for (int k = 0; k < RK; k++) a += Ss[r][k] * Rm[k][j];
        W[r][j] = a;
    }
    __syncthreads();
    for (int r = 0; r < 64; r++) {
        for (int c = t; c < ND; c += 256) {
            float a = Sw[(long)b * NR * ND + (long)(r0 + r) * ND + c];
            float s2 = 0.f;
#pragma unroll
            for (int j = 0; j < RK; j++) s2 += W[r][j] * Qs[c][j];
            out[(long)b * NR * ND + (long)(r0 + r) * ND + c] = a + s2;
        }
    }
}

// ---------------- mean cosine ----------------
__global__ __launch_bounds__(256)
void cos_kernel(const float* __restrict__ out, const float* __restrict__ tgt,
                float* __restrict__ acc)
{
    int row = blockIdx.x * 4 + (threadIdx.x >> 6);
    int lane = threadIdx.x & 63;
    const float* a = out + (long)row * ND;
    const float* tg = tgt + (long)row * ND;
    float sd = 0.f, sa = 0.f, st = 0.f;
    for (int i = lane; i < ND; i += 64) {
        float av = a[i], tv = tg[i];
        sd += av * tv; sa += av * av; st += tv * tv;
    }
#pragma unroll
    for (int off = 32; off > 0; off >>= 1) {
        sd += __shfl_down(sd, off); sa += __shfl_down(sa, off); st += __shfl_down(st, off);
    }
    __shared__ float part[4];
    if (lane == 0) part[threadIdx.x >> 6] = sd / (sqrtf(sa) * sqrtf(st) + 1e-8f);
    __syncthreads();
    if (threadIdx.x == 0) atomicAdd(acc, part[0] + part[1] + part[2] + part[3]);
}

__global__ void finalize_kernel(const float* __restrict__ acc, float* __restrict__ out)
{
    out[0] = acc[0] / 32768.0f;
}

// ---------------- host ----------------
static inline void launch_gemm(int TA, const float* A, const float* Bm, float* C,
                               int M, int N, int K, long sA, long sB, long sC,
                               int lda, int ldb, int ldc, int mode,
                               const float* scale, hipStream_t stream)
{
    dim3 grid((M / 128) * (N / 128), BATCH);
    if (TA)
        gemm_kernel<1><<<grid, dim3(256), 0, stream>>>(A, Bm, C, M, N, K, sA, sB, sC, lda, ldb, ldc, mode, scale);
    else
        gemm_kernel<0><<<grid, dim3(256), 0, stream>>>(A, Bm, C, M, N, K, sA, sB, sC, lda, ldb, ldc, mode, scale);
}

extern "C" void kernel_launch(void* const* d_in, const int* in_sizes, int n_in,
                              void* d_out, int out_size, void* d_ws, size_t ws_size,
                              hipStream_t stream)
{
    const float* src = (const float*)d_in[0];
    const float* tgt = (const float*)d_in[1];
    float* out = (float*)d_out;
    float* ws = (float*)d_ws;

    float* A0 = ws;
    float* A1 = ws + 1 * SZC;
    float* A2 = ws + 2 * SZC;
    float* A3 = ws + 3 * SZC;
    float* A4 = ws + 4 * SZC;
    float* S5 = ws + 5 * SZC;
    float* nrm_s = S5;
    float* nrm_t = S5 + 64;
    float* dd = S5 + 128;
    float* ee = dd + BATCH * ND;
    float* tt = ee + BATCH * ND;
    float* lam = tt + BATCH * ND;
    float* accp = lam + BATCH * RK;

    float* Tm = out;                 // transient NS "T" buffer lives in d_out
    float* SW = A0;                  // 512x384 per batch (spans A0..A1)
    float* TW = A0 + (long)BATCH * NR * ND;
    float* G  = A3;
    // C-region in A4:
    float* scr = A4;                                   // 6 * 384 * 1536
    float* Qp  = A4 + 6L * ND * SSTR;
    float* Spp = Qp + (long)BATCH * ND * RK;
    float* Tpp = Spp + (long)BATCH * NR * RK;
    float* Rp  = Tpp + (long)BATCH * NR * RK;
    float* Wg  = Rp + (long)BATCH * RK * RK;           // PNB*ND per batch (1.57M floats)
    float* yarr = scr + 5L * ND * SSTR;

    const long sXin = (long)NR * ND;     // 196608
    const long sSq  = (long)ND * ND;     // 147456

    // ---- phase S: covariance + Newton-Schulz inverse sqrt ----
    launch_gemm(1, src, src, A0, ND, ND, NR, sXin, sXin, sSq, ND, ND, ND, MODE_COV, nullptr, stream);
    frob_kernel<<<BATCH, 256, 0, stream>>>(A0, nrm_s);
    init_kernel<<<dim3(4096), 256, 0, stream>>>(A0, A2, nrm_s);
    {
        float* Y = A0; float* Yo = A1; float* Z = A2; float* Zo = A3;
        for (int it = 0; it < NSI; it++) {
            launch_gemm(0, Z, Y, Tm, ND, ND, ND, sSq, sSq, sSq, ND, ND, ND, MODE_NST, nullptr, stream);
            launch_gemm(0, Y, Tm, Yo, ND, ND, ND, sSq, sSq, sSq, ND, ND, ND, MODE_PLAIN, nullptr, stream);
            launch_gemm(0, Tm, Z, Zo, ND, ND, ND, sSq, sSq, sSq, ND, ND, ND, MODE_PLAIN, nullptr, stream);
            float* tmp = Y; Y = Yo; Yo = tmp;
            tmp = Z; Z = Zo; Zo = tmp;
        }
        // Z_s ends in A3
    }
    // ---- phase T ----
    launch_gemm(1, tgt, tgt, A0, ND, ND, NR, sXin, sXin, sSq, ND, ND, ND, MODE_COV, nullptr, stream);
    frob_kernel<<<BATCH, 256, 0, stream>>>(A0, nrm_t);
    init_kernel<<<dim3(4096), 256, 0, stream>>>(A0, A2, nrm_t);
    {
        float* Y = A0; float* Yo = A1; float* Z = A2; float* Zo = A4;
        for (int it = 0; it < NSI; it++) {
            launch_gemm(0, Z, Y, Tm, ND, ND, ND, sSq, sSq, sSq, ND, ND, ND, MODE_NST, nullptr, stream);
            launch_gemm(0, Y, Tm, Yo, ND, ND, ND, sSq, sSq, sSq, ND, ND, ND, MODE_PLAIN, nullptr, stream);
            launch_gemm(0, Tm, Z, Zo, ND, ND, ND, sSq, sSq, sSq, ND, ND, ND, MODE_PLAIN, nullptr, stream);
            float* tmp = Y; Y = Yo; Yo = tmp;
            tmp = Z; Z = Zo; Zo = tmp;
        }
        // Z_t ends in A4
    }
    // ---- whiten ----
    launch_gemm(0, src, A3, SW, NR, ND, ND, sXin, sSq, sXin, ND, ND, ND, MODE_SCALE, nrm_s, stream);
    launch_gemm(0, tgt, A4, TW, NR, ND, ND, sXin, sSq, sXin, ND, ND, ND, MODE_SCALE, nrm_t, stream);
    // ---- G = S_w^T S_w + T_w^T T_w ----
    launch_gemm(1, SW, SW, G, ND, ND, NR, sXin, sXin, sSq, ND, ND, ND, MODE_PLAIN, nullptr, stream);
    launch_gemm(1, TW, TW, G, ND, ND, NR, sXin, sXin, sSq, ND, ND, ND, MODE_ACC, nullptr, stream);
    // ---- blocked tridiagonalization: panels + full-device trailing updates ----
    for (int p = 0; p < ND / PNB; p++) {
        tridiag_panel<<<BATCH, 768, 0, stream>>>(G, dd, ee, tt, Wg, p * PNB);
        int k1 = (p + 1) * PNB;
        if (k1 < ND - 2) {
            int tiles = (ND - k1) / 64;
            syr2k_update<<<dim3(tiles * tiles, BATCH), 256, 0, stream>>>(G, Wg, p * PNB);
        }
    }
    eigvals_kernel<<<BATCH, 64, 0, stream>>>(dd, ee, lam);
    invit_kernel<<<BATCH, 64, 0, stream>>>(dd, ee, lam, scr);
    orthbt_kernel<<<BATCH, 384, 0, stream>>>(yarr, G, tt, Qp);
    // ---- projections, Procrustes, output ----
    proj_kernel<<<dim3(2, BATCH), 256, 0, stream>>>(SW, Qp, Spp);
    proj_kernel<<<dim3(2, BATCH), 256, 0, stream>>>(TW, Qp, Tpp);
    polar_kernel<<<BATCH, 256, 0, stream>>>(Spp, Tpp, Rp);
    align_kernel<<<dim3(8, BATCH), 256, 0, stream>>>(SW, Spp, Rp, Qp, out);
    hipMemsetAsync((void*)accp, 0, 4, stream);
    cos_kernel<<<dim3(8192), 256, 0, stream>>>(out, tgt, accp);
    finalize_kernel<<<1, 1, 0, stream>>>(accp, out + (long)BATCH * NR * ND);
    (void)in_sizes; (void)n_in; (void)out_size; (void)ws_size;
}

// Round 6
// 9755.549 us; speedup vs baseline: 1.3298x; 1.3298x over previous
//
#include <hip/hip_runtime.h>
#include <math.h>

static constexpr int BATCH = 64;
static constexpr int NR  = 512;    // rows per matrix (n)
static constexpr int ND  = 384;    // feature dim (N)
static constexpr int RK  = 24;     // rank
static constexpr int NSI = 5;      // Newton-Schulz iters (whitening)
static constexpr int POLAR_ITERS = 36;
static constexpr int PNB = 64;     // tridiag panel width
static constexpr long SZC = (long)BATCH * ND * ND;      // 9,437,184 floats
static constexpr int SSTR = BATCH * RK;                 // 1536 (inverse-iter solve stride)

#define MODE_PLAIN 0
#define MODE_COV   1
#define MODE_NST   2
#define MODE_SCALE 3
#define MODE_ACC   4

typedef _Float16 half8 __attribute__((ext_vector_type(8)));
typedef _Float16 half4 __attribute__((ext_vector_type(4)));
typedef float floatx4 __attribute__((ext_vector_type(4)));

// ---------------- batched split-fp16 MFMA GEMM (128x128 tile, 4 waves) ----------
// C = A*B (TA=0, A row-major MxK) or C = A^T*B (TA=1, A stored KxM row-major).
// fp32 emulated via 2-term fp16 split, 3 MFMA passes: lo*hi + hi*lo + hi*hi.
// mfma_f32_16x16x32_f16 layouts (HW-verified, dtype-independent):
//   A-frag: A[m=lane&15][k=quad*8+j];  B-frag: B[k=quad*8+j][n=lane&15]
//   C/D:    col=lane&15, row=quad*4+reg
template<int TA>
__global__ __launch_bounds__(256)
void gemm_kernel(const float* __restrict__ Ag, const float* __restrict__ Bg,
                 float* __restrict__ Cg, int M, int N, int K,
                 long sA, long sB, long sC, int lda, int ldb, int ldc,
                 int mode, const float* __restrict__ scale)
{
    const int batch = blockIdx.y;
    const int tilesN = N >> 7;            // N/128
    const int tx = blockIdx.x % tilesN;
    const int ty = blockIdx.x / tilesN;
    const int n0 = tx * 128, m0 = ty * 128;
    const float* A = Ag + (long)batch * sA;
    const float* Bm = Bg + (long)batch * sB;
    float* C = Cg + (long)batch * sC;

    // [dim][k] layout, k contiguous -> fragment load = one ds_read_b128
    __shared__ _Float16 Ah[128][40], Al[128][40];
    __shared__ _Float16 Bh[128][40], Bl[128][40];

    const int tid = threadIdx.x;
    const int wave = tid >> 6, lane = tid & 63;
    const int wm0 = (wave >> 1) * 64, wn0 = (wave & 1) * 64;
    const int fm = lane & 15;       // frag row (A) / col (B,D)
    const int fq = lane >> 4;       // quad

    floatx4 acc[4][4];
#pragma unroll
    for (int i = 0; i < 4; i++)
#pragma unroll
        for (int j = 0; j < 4; j++) acc[i][j] = (floatx4){0.f, 0.f, 0.f, 0.f};

    for (int k0 = 0; k0 < K; k0 += 32) {
        // ---- stage A ----
        if (TA == 0) {
            // A[m0+row][k0+kq..] : float4 along k, write half4 contiguous
#pragma unroll
            for (int q = 0; q < 4; q++) {
                int idx = tid + q * 256;          // 1024 float4 = 128x32
                int row = idx >> 3, kq = (idx & 7) * 4;
                float4 v = *(const float4*)&A[(long)(m0 + row) * lda + k0 + kq];
                _Float16 h0 = (_Float16)v.x; _Float16 l0 = (_Float16)(v.x - (float)h0);
                _Float16 h1 = (_Float16)v.y; _Float16 l1 = (_Float16)(v.y - (float)h1);
                _Float16 h2 = (_Float16)v.z; _Float16 l2 = (_Float16)(v.z - (float)h2);
                _Float16 h3 = (_Float16)v.w; _Float16 l3 = (_Float16)(v.w - (float)h3);
                half4 hv, lv;
                hv[0] = h0; hv[1] = h1; hv[2] = h2; hv[3] = h3;
                lv[0] = l0; lv[1] = l1; lv[2] = l2; lv[3] = l3;
                *(half4*)&Ah[row][kq] = hv;
                *(half4*)&Al[row][kq] = lv;
            }
        } else {
            // A^T: need As[m][k] = A[k0+k][m0+m]; load scalar coalesced along m,
            // 16 k-values per thread, write half4 runs along k
            int m = tid & 127, kb = (tid >> 7) * 16;
            _Float16 hbuf[16], lbuf[16];
#pragma unroll
            for (int i = 0; i < 16; i++) {
                float v = A[(long)(k0 + kb + i) * lda + m0 + m];
                _Float16 hh = (_Float16)v;
                hbuf[i] = hh; lbuf[i] = (_Float16)(v - (float)hh);
            }
#pragma unroll
            for (int i = 0; i < 16; i += 4) {
                half4 hv, lv;
                hv[0] = hbuf[i]; hv[1] = hbuf[i + 1]; hv[2] = hbuf[i + 2]; hv[3] = hbuf[i + 3];
                lv[0] = lbuf[i]; lv[1] = lbuf[i + 1]; lv[2] = lbuf[i + 2]; lv[3] = lbuf[i + 3];
                *(half4*)&Ah[m][kb + i] = hv;
                *(half4*)&Al[m][kb + i] = lv;
            }
        }
        // ---- stage B: need Bs[n][k] = B[k0+k][n0+n] (transpose) ----
        {
            int n = tid & 127, kb = (tid >> 7) * 16;
            _Float16 hbuf[16], lbuf[16];
#pragma unroll
            for (int i = 0; i < 16; i++) {
                float v = Bm[(long)(k0 + kb + i) * ldb + n0 + n];
                _Float16 hh = (_Float16)v;
                hbuf[i] = hh; lbuf[i] = (_Float16)(v - (float)hh);
            }
#pragma unroll
            for (int i = 0; i < 16; i += 4) {
                half4 hv, lv;
                hv[0] = hbuf[i]; hv[1] = hbuf[i + 1]; hv[2] = hbuf[i + 2]; hv[3] = hbuf[i + 3];
                lv[0] = lbuf[i]; lv[1] = lbuf[i + 1]; lv[2] = lbuf[i + 2]; lv[3] = lbuf[i + 3];
                *(half4*)&Bh[n][kb + i] = hv;
                *(half4*)&Bl[n][kb + i] = lv;
            }
        }
        __syncthreads();

        // ---- fragments + MFMA ----
        half8 ah[4], alv[4], bh[4], blv[4];
#pragma unroll
        for (int mt = 0; mt < 4; mt++) {
            ah[mt]  = *(const half8*)&Ah[wm0 + mt * 16 + fm][fq * 8];
            alv[mt] = *(const half8*)&Al[wm0 + mt * 16 + fm][fq * 8];
        }
#pragma unroll
        for (int nt = 0; nt < 4; nt++) {
            bh[nt]  = *(const half8*)&Bh[wn0 + nt * 16 + fm][fq * 8];
            blv[nt] = *(const half8*)&Bl[wn0 + nt * 16 + fm][fq * 8];
        }
#pragma unroll
        for (int mt = 0; mt < 4; mt++) {
#pragma unroll
            for (int nt = 0; nt < 4; nt++) {
                floatx4 a = acc[mt][nt];
                a = __builtin_amdgcn_mfma_f32_16x16x32_f16(alv[mt], bh[nt], a, 0, 0, 0);
                a = __builtin_amdgcn_mfma_f32_16x16x32_f16(ah[mt], blv[nt], a, 0, 0, 0);
                a = __builtin_amdgcn_mfma_f32_16x16x32_f16(ah[mt], bh[nt], a, 0, 0, 0);
                acc[mt][nt] = a;
            }
        }
        __syncthreads();
    }

    float scl = 1.f;
    if (mode == MODE_SCALE) scl = 1.0f / sqrtf(scale[batch]);

#pragma unroll
    for (int mt = 0; mt < 4; mt++) {
#pragma unroll
        for (int nt = 0; nt < 4; nt++) {
            int gn = n0 + wn0 + nt * 16 + fm;
#pragma unroll
            for (int r = 0; r < 4; r++) {
                int gm = m0 + wm0 + mt * 16 + fq * 4 + r;
                float v = acc[mt][nt][r];
                float* cp = C + (long)gm * ldc + gn;
                if (mode == MODE_COV)      v = v * (1.0f / 512.0f) + ((gm == gn) ? 1e-5f : 0.f);
                else if (mode == MODE_NST) v = ((gm == gn) ? 1.5f : 0.f) - 0.5f * v;
                else if (mode == MODE_SCALE) v *= scl;
                else if (mode == MODE_ACC) v += *cp;
                *cp = v;
            }
        }
    }
}

// ---------------- Frobenius norm per batch ----------------
__global__ __launch_bounds__(256)
void frob_kernel(const float* __restrict__ Cm, float* __restrict__ nrm)
{
    int b = blockIdx.x;
    const float* p = Cm + (long)b * ND * ND;
    float s = 0.f;
    for (int i = threadIdx.x; i < ND * ND; i += 256) { float v = p[i]; s += v * v; }
    __shared__ float red[256];
    red[threadIdx.x] = s; __syncthreads();
    for (int off = 128; off > 0; off >>= 1) {
        if (threadIdx.x < off) red[threadIdx.x] += red[threadIdx.x + off];
        __syncthreads();
    }
    if (threadIdx.x == 0) nrm[b] = sqrtf(red[0]);
}

// ---------------- Y0 = C/normC (in place), Z0 = I ----------------
__global__ __launch_bounds__(256)
void init_kernel(float* __restrict__ Y, float* __restrict__ Z, const float* __restrict__ nrm)
{
    const int total = BATCH * ND * ND;
    for (int idx = blockIdx.x * 256 + threadIdx.x; idx < total; idx += gridDim.x * 256) {
        int b = idx / (ND * ND);
        int rem = idx - b * (ND * ND);
        int r = rem / ND, c = rem - r * ND;
        Y[idx] = Y[idx] / nrm[b];
        Z[idx] = (r == c) ? 1.f : 0.f;
    }
}

// ---------------- block reduction over 768 threads ----------------
__device__ __forceinline__ float bred768(float v, float* red12, int t)
{
#pragma unroll
    for (int off = 32; off > 0; off >>= 1) v += __shfl_down(v, off);
    if ((t & 63) == 0) red12[t >> 6] = v;
    __syncthreads();
    float r = 0.f;
#pragma unroll
    for (int i = 0; i < 12; i++) r += red12[i];
    __syncthreads();
    return r;
}

// ---------------- Blocked Householder tridiagonalization: panel kernel ----------
__global__ __launch_bounds__(768)
void tridiag_panel(float* __restrict__ Gall, float* __restrict__ dA,
                   float* __restrict__ eA, float* __restrict__ tauA,
                   float* __restrict__ Wgall, int k0)
{
    int b = blockIdx.x;
    float* A = Gall + (long)b * ND * ND;
    float* Wg = Wgall + (long)b * (PNB * ND);
    float* d = dA + b * ND; float* e = eA + b * ND; float* tau = tauA + b * ND;
    const int t = threadIdx.x;
    const int h = (t >= ND) ? 1 : 0;
    const int c = t - h * ND;            // 0..383
    __shared__ float u_s[ND];
    __shared__ float pp[2][ND];
    __shared__ float ukv[PNB], wkv[PNB], al[PNB], be[PNB];
    __shared__ float red12[12];
    __shared__ float s_tau;

    const int jcnt = min(PNB, ND - 2 - k0);

    for (int j = 0; j < jcnt; j++) {
        const int k = k0 + j;
        const int m = ND - 1 - k;
        if (t < j) { ukv[t] = A[(long)(k0 + t) * ND + k]; wkv[t] = Wg[t * ND + k]; }
        __syncthreads();
        float x = 0.f;
        if (!h && c < m) {
            x = A[(long)k * ND + (k + 1) + c];
            for (int l = 0; l < j; l++) {
                x -= ukv[l] * Wg[l * ND + (k + 1) + c]
                   + wkv[l] * A[(long)(k0 + l) * ND + (k + 1) + c];
            }
            u_s[c] = x;
        }
        float sigma = bred768(x * x, red12, t);
        if (t == 0) {
            float v0 = u_s[0];
            float normx = sqrtf(sigma);
            float alpha = (v0 >= 0.f) ? -normx : normx;
            float denom = sigma - alpha * v0;
            float tk = (denom > 1e-30f) ? 1.f / denom : 0.f;
            s_tau = tk;
            float diag = A[(long)k * ND + k];
            for (int l = 0; l < j; l++) diag -= 2.f * ukv[l] * wkv[l];
            e[k] = alpha; tau[k] = tk; d[k] = diag;
            u_s[0] = v0 - alpha;
        }
        __syncthreads();
        const float tk = s_tau;
        const int mh = m >> 1;
        const int i0 = h ? mh : 0;
        const int i1 = h ? m : mh;

        // partial matvec over the clean stored trailing block (8-deep unroll, MLP)
        float p = 0.f;
        if (c < m) {
            const float* col = A + (long)(k + 1) * ND + (k + 1) + c;
            int i = i0;
            for (; i + 8 <= i1; i += 8) {
                p += col[(long)(i    ) * ND] * u_s[i]
                   + col[(long)(i + 1) * ND] * u_s[i + 1]
                   + col[(long)(i + 2) * ND] * u_s[i + 2]
                   + col[(long)(i + 3) * ND] * u_s[i + 3]
                   + col[(long)(i + 4) * ND] * u_s[i + 4]
                   + col[(long)(i + 5) * ND] * u_s[i + 5]
                   + col[(long)(i + 6) * ND] * u_s[i + 6]
                   + col[(long)(i + 7) * ND] * u_s[i + 7];
            }
            for (; i < i1; i++) p += col[(long)i * ND] * u_s[i];
        }
        pp[h][c] = p;
        // wave-parallel dots: al[l] = w_l . u, be[l] = u_l . u
        {
            int wv = t >> 6, ln = t & 63;
            for (int l = wv; l < j; l += 12) {
                float sa = 0.f, sb = 0.f;
                const float* wrow = Wg + l * ND + (k + 1);
                const float* urow = A + (long)(k0 + l) * ND + (k + 1);
                for (int i = ln; i < m; i += 64) { sa += wrow[i] * u_s[i]; sb += urow[i] * u_s[i]; }
#pragma unroll
                for (int off = 32; off > 0; off >>= 1) {
                    sa += __shfl_down(sa, off); sb += __shfl_down(sb, off);
                }
                if (ln == 0) { al[l] = sa; be[l] = sb; }
            }
        }
        __syncthreads();
        float contrib = 0.f, pc = 0.f;
        if (!h && c < m) {
            pc = pp[0][c] + pp[1][c];
            for (int l = 0; l < j; l++) {
                pc -= al[l] * A[(long)(k0 + l) * ND + (k + 1) + c]
                    + be[l] * Wg[l * ND + (k + 1) + c];
            }
            pc *= tk;
            contrib = u_s[c] * pc;
        }
        float dotup = bred768(contrib, red12, t);
        float sc = 0.5f * tk * dotup;
        if (!h && c < m) {
            float w = pc - sc * u_s[c];
            Wg[j * ND + (k + 1) + c] = w;
            A[(long)k * ND + (k + 1) + c] = u_s[c];
        }
        __syncthreads();
    }
    if (k0 + PNB >= ND - 2 && t == 0) {
        float d0 = A[(long)(ND - 2) * ND + (ND - 2)];
        float e0 = A[(long)(ND - 2) * ND + (ND - 1)];
        float d1 = A[(long)(ND - 1) * ND + (ND - 1)];
        for (int l = 0; l < jcnt; l++) {
            float u0 = A[(long)(k0 + l) * ND + (ND - 2)];
            float u1 = A[(long)(k0 + l) * ND + (ND - 1)];
            float w0 = Wg[l * ND + (ND - 2)];
            float w1 = Wg[l * ND + (ND - 1)];
            d0 -= 2.f * u0 * w0;
            e0 -= u0 * w1 + w0 * u1;
            d1 -= 2.f * u1 * w1;
        }
        d[ND - 2] = d0; d[ND - 1] = d1; e[ND - 2] = e0;
        e[ND - 1] = 0.f; tau[ND - 2] = 0.f; tau[ND - 1] = 0.f;
    }
}

// ---------------- trailing update: A -= U W^T + W U^T (full device) ----------
__global__ __launch_bounds__(256)
void syr2k_update(float* __restrict__ Gall, const float* __restrict__ Wgall, int k0)
{
    const int k1 = k0 + PNB;
    const int tiles = (ND - k1) >> 6;
    int b = blockIdx.y;
    int ti = blockIdx.x / tiles, tj = blockIdx.x % tiles;
    int i0 = k1 + ti * 64, c0 = k1 + tj * 64;
    float* A = Gall + (long)b * ND * ND;
    const float* Wg = Wgall + (long)b * (PNB * ND);

    __shared__ float Us[PNB][65], Ws[PNB][65], Uc[PNB][65], Wc[PNB][65];
    int t = threadIdx.x;
    for (int q = t; q < PNB * 16; q += 256) {
        int l = q >> 4, c4 = (q & 15) * 4;
        *(float4*)&Us[l][c4] = *(const float4*)&A[(long)(k0 + l) * ND + i0 + c4];
        *(float4*)&Ws[l][c4] = *(const float4*)&Wg[l * ND + i0 + c4];
        *(float4*)&Uc[l][c4] = *(const float4*)&A[(long)(k0 + l) * ND + c0 + c4];
        *(float4*)&Wc[l][c4] = *(const float4*)&Wg[l * ND + c0 + c4];
    }
    __syncthreads();
    int tr = t >> 4, tc = t & 15;
    float acc[4][4];
#pragma unroll
    for (int a = 0; a < 4; a++)
#pragma unroll
        for (int q = 0; q < 4; q++) acc[a][q] = 0.f;
    for (int l = 0; l < PNB; l++) {
        float ua[4], wa[4], ub[4], wb[4];
#pragma unroll
        for (int a = 0; a < 4; a++) {
            ua[a] = Us[l][tr * 4 + a]; wa[a] = Ws[l][tr * 4 + a];
            ub[a] = Uc[l][tc * 4 + a]; wb[a] = Wc[l][tc * 4 + a];
        }
#pragma unroll
        for (int a = 0; a < 4; a++)
#pragma unroll
            for (int q = 0; q < 4; q++) acc[a][q] += ua[a] * wb[q] + wa[a] * ub[q];
    }
#pragma unroll
    for (int a = 0; a < 4; a++) {
        float* crow = &A[(long)(i0 + tr * 4 + a) * ND + c0 + tc * 4];
        float4 old = *(const float4*)crow;
        old.x -= acc[a][0]; old.y -= acc[a][1]; old.z -= acc[a][2]; old.w -= acc[a][3];
        *(float4*)crow = old;
    }
}

// ---------------- Sturm bisection: top-24 eigenvalues ----------------
__global__ __launch_bounds__(64)
void eigvals_kernel(const float* __restrict__ dA, const float* __restrict__ eA,
                    float* __restrict__ lamA)
{
    int b = blockIdx.x, t = threadIdx.x;   // 64 threads
    __shared__ float d[ND], e2[ND], ea[ND], red[64];
    for (int i = t; i < ND; i += 64) {
        d[i] = dA[b * ND + i];
        float ev = eA[b * ND + i];
        ea[i] = fabsf(ev); e2[i] = ev * ev;
    }
    __syncthreads();
    float lo = 1e30f, hi = -1e30f;
    for (int i = t; i < ND; i += 64) {
        float r = ea[i] + ((i > 0) ? ea[i - 1] : 0.f);
        lo = fminf(lo, d[i] - r); hi = fmaxf(hi, d[i] + r);
    }
    red[t] = lo; __syncthreads();
    for (int off = 32; off > 0; off >>= 1) {
        if (t < off) red[t] = fminf(red[t], red[t + off]);
        __syncthreads();
    }
    lo = red[0]; __syncthreads();
    red[t] = hi; __syncthreads();
    for (int off = 32; off > 0; off >>= 1) {
        if (t < off) red[t] = fmaxf(red[t], red[t + off]);
        __syncthreads();
    }
    hi = red[0];
    if (t < RK) {
        int idx = ND - 1 - t;
        float a = lo, c = hi;
        for (int it = 0; it < 42; it++) {
            float mid = 0.5f * (a + c);
            int cnt = 0;
            float q = d[0] - mid;
            if (q < 0.f) cnt++;
            for (int i = 1; i < ND; i++) {
                float den = q;
                if (fabsf(den) < 1e-25f) den = (den < 0.f) ? -1e-25f : 1e-25f;
                q = d[i] - mid - e2[i - 1] / den;
                if (q < 0.f) cnt++;
            }
            if (cnt > idx) c = mid; else a = mid;
        }
        lamA[b * RK + t] = 0.5f * (a + c);
    }
}

// ---------------- tridiagonal inverse iteration (pivoted LU) ----------------
__global__ __launch_bounds__(64)
void invit_kernel(const float* __restrict__ dA, const float* __restrict__ eA,
                  const float* __restrict__ lamA, float* __restrict__ scr)
{
    int b = blockIdx.x, t = threadIdx.x;
    __shared__ float d[ND], e[ND];
    for (int i = t; i < ND; i += 64) { d[i] = dA[b * ND + i]; e[i] = eA[b * ND + i]; }
    __syncthreads();
    if (t >= RK) return;
    const int s = b * RK + t;
    float* ua = scr;
    float* ub = scr + (long)ND * SSTR;
    float* uc = scr + 2L * ND * SSTR;
    float* ul = scr + 3L * ND * SSTR;
    float* up = scr + 4L * ND * SSTR;
    float* y  = scr + 5L * ND * SSTR;
    float lam = lamA[s];
    float ai = d[0] - lam;
    float bc = e[0];
    for (int i = 0; i < ND - 1; i++) {
        float sub = e[i];
        float dn = d[i + 1] - lam;
        float en = (i + 1 < ND - 1) ? e[i + 1] : 0.f;
        long o = (long)i * SSTR + s;
        if (fabsf(ai) >= fabsf(sub)) {
            float aa = (ai == 0.f) ? 1e-20f : ai;
            float mlt = sub / aa;
            ua[o] = aa; ub[o] = bc; uc[o] = 0.f; ul[o] = mlt; up[o] = 0.f;
            ai = dn - mlt * bc;
            bc = en;
        } else {
            float mlt = ai / sub;
            ua[o] = sub; ub[o] = dn; uc[o] = en; ul[o] = mlt; up[o] = 1.f;
            ai = bc - mlt * dn;
            bc = -mlt * en;
        }
    }
    { long o = (long)(ND - 1) * SSTR + s; ua[o] = (ai == 0.f) ? 1e-20f : ai; ub[o] = 0.f; uc[o] = 0.f; }

    for (int pass = 0; pass < 2; pass++) {
        if (pass == 0) {
            for (int i = 0; i < ND; i++) {
                unsigned h = ((unsigned)i * 1103515245u) ^ ((unsigned)s * 747796405u);
                h *= 2654435769u; h ^= h >> 16;
                y[(long)i * SSTR + s] = ((float)(h & 0xFFFFu) * (1.f / 65536.f)) - 0.5f;
            }
        }
        for (int i = 0; i < ND - 1; i++) {
            long o = (long)i * SSTR + s, o1 = o + SSTR;
            float yi = y[o], y1 = y[o1];
            if (up[o] == 0.f) { y[o1] = y1 - ul[o] * yi; }
            else { y[o] = y1; y[o1] = yi - ul[o] * y1; }
        }
        {
            long oN = (long)(ND - 1) * SSTR + s;
            float xN = y[oN] / ua[oN]; y[oN] = xN;
            long o = oN - SSTR;
            float x1 = xN, x2 = 0.f;
            float xm = (y[o] - ub[o] * x1) / ua[o]; y[o] = xm; x2 = x1; x1 = xm;
            for (int i = ND - 3; i >= 0; i--) {
                o -= SSTR;
                float xi = (y[o] - ub[o] * x1 - uc[o] * x2) / ua[o];
                y[o] = xi; x2 = x1; x1 = xi;
            }
        }
        float nn = 0.f;
        for (int i = 0; i < ND; i++) { float v = y[(long)i * SSTR + s]; nn += v * v; }
        float inv = (nn > 0.f) ? 1.f / sqrtf(nn) : 0.f;
        for (int i = 0; i < ND; i++) y[(long)i * SSTR + s] *= inv;
    }
}

// ---------------- MGS + Householder back-transform (one WG per batch) ----------------
__device__ __forceinline__ float blockSum384(float v, float* red6, int t)
{
#pragma unroll
    for (int off = 32; off > 0; off >>= 1) v += __shfl_down(v, off);
    __syncthreads();
    if ((t & 63) == 0) red6[t >> 6] = v;
    __syncthreads();
    return red6[0] + red6[1] + red6[2] + red6[3] + red6[4] + red6[5];
}

__global__ __launch_bounds__(384)
void orthbt_kernel(const float* __restrict__ xx, const float* __restrict__ Gall,
                   const float* __restrict__ tauA, float* __restrict__ Qout)
{
    int b = blockIdx.x, t = threadIdx.x;   // 384 threads
    __shared__ float Y[ND][RK + 1];
    __shared__ float u[ND];
    __shared__ float red[ND];
    __shared__ float red6[8];
    __shared__ float sarr[RK];

    for (int j = 0; j < RK; j++) Y[t][j] = xx[(long)t * SSTR + b * RK + j];
    __syncthreads();

    for (int j = 0; j < RK; j++) {
        float nv = blockSum384(Y[t][j] * Y[t][j], red6, t);
        float inv = (nv > 1e-30f) ? 1.f / sqrtf(nv) : 0.f;
        Y[t][j] *= inv;
        for (int l = j + 1; l < RK; l++) {
            float dt = blockSum384(Y[t][j] * Y[t][l], red6, t);
            Y[t][l] -= dt * Y[t][j];
        }
    }
    __syncthreads();

    const float* A = Gall + (long)b * ND * ND;
    const float* tau = tauA + b * ND;
    const int col = t % RK;       // 384 = 16*24
    const int sl = t / RK;
    for (int k = ND - 3; k >= 0; k--) {
        int m = ND - 1 - k;
        for (int i = t; i < m; i += 384) u[i] = A[(long)k * ND + (k + 1 + i)];
        float tk = tau[k];
        __syncthreads();
        float p = 0.f;
        for (int i = sl; i < m; i += 16) p += u[i] * Y[k + 1 + i][col];
        red[col * 16 + sl] = p; __syncthreads();
        if (sl == 0) {
            float ssum = 0.f;
            for (int q = 0; q < 16; q++) ssum += red[col * 16 + q];
            sarr[col] = tk * ssum;
        }
        __syncthreads();
        float sv = sarr[col];
        for (int i = sl; i < m; i += 16) Y[k + 1 + i][col] -= u[i] * sv;
        __syncthreads();
    }
    for (int l = t; l < ND * RK; l += 384) {
        int i = l / RK, j = l - i * RK;
        Qout[(long)b * ND * RK + l] = Y[i][j];
    }
}

// ---------------- Sp = X_w @ Q ----------------
__global__ __launch_bounds__(256)
void proj_kernel(const float* __restrict__ Xw, const float* __restrict__ Qall,
                 float* __restrict__ P)
{
    int b = blockIdx.y;
    int r0 = blockIdx.x * 256;
    __shared__ float Qs[ND][RK + 1];
    const float* Q = Qall + (long)b * ND * RK;
    for (int l = threadIdx.x; l < ND * RK; l += 256) {
        int i = l / RK, j = l - i * RK;
        Qs[i][j] = Q[l];
    }
    __syncthreads();
    int r = r0 + threadIdx.x;
    const float* X = Xw + (long)b * NR * ND + (long)r * ND;
    float acc[RK];
#pragma unroll
    for (int j = 0; j < RK; j++) acc[j] = 0.f;
    for (int k = 0; k < ND; k++) {
        float xv = X[k];
#pragma unroll
        for (int j = 0; j < RK; j++) acc[j] += xv * Qs[k][j];
    }
    float* Pr = P + (long)b * NR * RK + (long)r * RK;
#pragma unroll
    for (int j = 0; j < RK; j++) Pr[j] = acc[j];
}

// ---------------- M = Sp^T Tp ; R = polar(M) via Newton-Schulz ; write R - I ----------------
__global__ __launch_bounds__(256)
void polar_kernel(const float* __restrict__ Sp, const float* __restrict__ Tp,
                  float* __restrict__ RmI)
{
    int b = blockIdx.x, t = threadIdx.x;
    __shared__ float Sb[128][RK + 1], Tb[128][RK + 1];
    __shared__ float Xm[RK][RK + 1], Bm[RK][RK + 1], Mm[RK][RK + 1];
    __shared__ float red[256];

    float accM[3] = {0.f, 0.f, 0.f};
    for (int c = 0; c < 4; c++) {
        for (int l = t; l < 128 * RK; l += 256) {
            int row = l / RK, colj = l - row * RK;
            Sb[row][colj] = Sp[(long)b * NR * RK + (long)(c * 128 + row) * RK + colj];
            Tb[row][colj] = Tp[(long)b * NR * RK + (long)(c * 128 + row) * RK + colj];
        }
        __syncthreads();
        for (int q = 0; q < 3; q++) {
            int e = t + q * 256;
            if (e < RK * RK) {
                int r = e / RK, s2 = e - r * RK;
                float a = 0.f;
                for (int n = 0; n < 128; n++) a += Sb[n][r] * Tb[n][s2];
                accM[q] += a;
            }
        }
        __syncthreads();
    }
    float ss = 0.f;
    for (int q = 0; q < 3; q++) {
        int e = t + q * 256;
        if (e < RK * RK) {
            int r = e / RK, s2 = e - r * RK;
            Mm[r][s2] = accM[q];
            ss += accM[q] * accM[q];
        }
    }
    red[t] = ss; __syncthreads();
    for (int off = 128; off > 0; off >>= 1) {
        if (t < off) red[t] += red[t + off];
        __syncthreads();
    }
    float fro = sqrtf(red[0]);
    float inv = (fro > 1e-30f) ? 1.f / fro : 0.f;
    for (int q = 0; q < 3; q++) {
        int e = t + q * 256;
        if (e < RK * RK) { int r = e / RK, s2 = e - r * RK; Xm[r][s2] = Mm[r][s2] * inv; }
    }
    __syncthreads();
    for (int it = 0; it < POLAR_ITERS; it++) {
        for (int q = 0; q < 3; q++) {
            int e = t + q * 256;
            if (e < RK * RK) {
                int r = e / RK, s2 = e - r * RK;
                float a = 0.f;
                for (int k = 0; k < RK; k++) a += Xm[k][r] * Xm[k][s2];
                Bm[r][s2] = a;
            }
        }
        __syncthreads();
        for (int q = 0; q < 3; q++) {
            int e = t + q * 256;
            if (e < RK * RK) {
                int r = e / RK, s2 = e - r * RK;
                float a = 0.f;
                for (int k = 0; k < RK; k++) a += Xm[r][k] * Bm[k][s2];
                Mm[r][s2] = 1.5f * Xm[r][s2] - 0.5f * a;
            }
        }
        __syncthreads();
        for (int q = 0; q < 3; q++) {
            int e = t + q * 256;
            if (e < RK * RK) { int r = e / RK, s2 = e - r * RK; Xm[r][s2] = Mm[r][s2]; }
        }
        __syncthreads();
    }
    for (int q = 0; q < 3; q++) {
        int e = t + q * 256;
        if (e < RK * RK) {
            int r = e / RK, s2 = e - r * RK;
            RmI[(long)b * RK * RK + e] = Xm[r][s2] - ((r == s2) ? 1.f : 0.f);
        }
    }
}

// ---------------- aligned = S_w + Sp (R-I) Q^T  (writes d_out) ----------------
__global__ __launch_bounds__(256)
void align_kernel(const float* __restrict__ Sw, const float* __restrict__ Sp,
                  const float* __restrict__ RmI, const float* __restrict__ Qall,
                  float* __restrict__ out)
{
    int b = blockIdx.y;
    int r0 = blockIdx.x * 64;
    int t = threadIdx.x;
    __shared__ float Qs[ND][RK + 1];
    __shared__ float Rm[RK][RK + 1];
    __shared__ float Ss[64][RK + 1];
    __shared__ float W[64][RK + 1];

    for (int l = t; l < ND * RK; l += 256) {
        int i = l / RK, j = l - i * RK;
        Qs[i][j] = Qall[(long)b * ND * RK + l];
    }
    for (int l = t; l < RK * RK; l += 256) {
        int i = l / RK, j = l - i * RK;
        Rm[i][j] = RmI[(long)b * RK * RK + l];
    }
    for (int l = t; l < 64 * RK; l += 256) {
        int i = l / RK, j = l - i * RK;
        Ss[i][j] = Sp[(long)b * NR * RK + (long)(r0 + i) * RK + j];
    }
    __syncthreads();
    for (int l = t; l < 64 * RK; l += 256) {
        int r = l / RK, j = l - r * RK;
        float a = 0.f;
        for (int k = 0; k < RK; k++) a += Ss[r][k] * Rm[k][j];
        W[r][j] = a;
    }
    __syncthreads();
    for (int r = 0; r < 64; r++) {
        for (int c = t; c < ND; c += 256) {
            float a = Sw[(long)b * NR * ND + (long)(r0 + r) * ND + c];
            float s2 = 0.f;
#pragma unroll
            for (int j = 0; j < RK; j++) s2 += W[r][j] * Qs[c][j];
            out[(long)b * NR * ND + (long)(r0 + r) * ND + c] = a + s2;
        }
    }
}

// ---------------- mean cosine ----------------
__global__ __launch_bounds__(256)
void cos_kernel(const float* __restrict__ out, const float* __restrict__ tgt,
                float* __restrict__ acc)
{
    int row = blockIdx.x * 4 + (threadIdx.x >> 6);
    int lane = threadIdx.x & 63;
    const float* a = out + (long)row * ND;
    const float* tg = tgt + (long)row * ND;
    float sd = 0.f, sa = 0.f, st = 0.f;
    for (int i = lane; i < ND; i += 64) {
        float av = a[i], tv = tg[i];
        sd += av * tv; sa += av * av; st += tv * tv;
    }
#pragma unroll
    for (int off = 32; off > 0; off >>= 1) {
        sd += __shfl_down(sd, off); sa += __shfl_down(sa, off); st += __shfl_down(st, off);
    }
    __shared__ float part[4];
    if (lane == 0) part[threadIdx.x >> 6] = sd / (sqrtf(sa) * sqrtf(st) + 1e-8f);
    __syncthreads();
    if (threadIdx.x == 0) atomicAdd(acc, part[0] + part[1] + part[2] + part[3]);
}

__global__ void finalize_kernel(const float* __restrict__ acc, float* __restrict__ out)
{
    out[0] = acc[0] / 32768.0f;
}

// ---------------- host ----------------
static inline void launch_gemm(int TA, const float* A, const float* Bm, float* C,
                               int M, int N, int K, long sA, long sB, long sC,
                               int lda, int ldb, int ldc, int mode,
                               const float* scale, hipStream_t stream)
{
    dim3 grid((M / 128) * (N / 128), BATCH);
    if (TA)
        gemm_kernel<1><<<grid, dim3(256), 0, stream>>>(A, Bm, C, M, N, K, sA, sB, sC, lda, ldb, ldc, mode, scale);
    else
        gemm_kernel<0><<<grid, dim3(256), 0, stream>>>(A, Bm, C, M, N, K, sA, sB, sC, lda, ldb, ldc, mode, scale);
}

extern "C" void kernel_launch(void* const* d_in, const int* in_sizes, int n_in,
                              void* d_out, int out_size, void* d_ws, size_t ws_size,
                              hipStream_t stream)
{
    const float* src = (const float*)d_in[0];
    const float* tgt = (const float*)d_in[1];
    float* out = (float*)d_out;
    float* ws = (float*)d_ws;

    float* A0 = ws;
    float* A1 = ws + 1 * SZC;
    float* A2 = ws + 2 * SZC;
    float* A3 = ws + 3 * SZC;
    float* A4 = ws + 4 * SZC;
    float* S5 = ws + 5 * SZC;
    float* nrm_s = S5;
    float* nrm_t = S5 + 64;
    float* dd = S5 + 128;
    float* ee = dd + BATCH * ND;
    float* tt = ee + BATCH * ND;
    float* lam = tt + BATCH * ND;
    float* accp = lam + BATCH * RK;

    float* Tm = out;                 // transient NS "T" buffer lives in d_out
    float* SW = A0;                  // 512x384 per batch (spans A0..A1)
    float* TW = A0 + (long)BATCH * NR * ND;
    float* G  = A3;
    float* scr = A4;                                   // 6 * 384 * 1536
    float* Qp  = A4 + 6L * ND * SSTR;
    float* Spp = Qp + (long)BATCH * ND * RK;
    float* Tpp = Spp + (long)BATCH * NR * RK;
    float* Rp  = Tpp + (long)BATCH * NR * RK;
    float* Wg  = Rp + (long)BATCH * RK * RK;           // PNB*ND per batch
    float* yarr = scr + 5L * ND * SSTR;

    const long sXin = (long)NR * ND;     // 196608
    const long sSq  = (long)ND * ND;     // 147456

    // ---- phase S: covariance + Newton-Schulz inverse sqrt ----
    launch_gemm(1, src, src, A0, ND, ND, NR, sXin, sXin, sSq, ND, ND, ND, MODE_COV, nullptr, stream);
    frob_kernel<<<BATCH, 256, 0, stream>>>(A0, nrm_s);
    init_kernel<<<dim3(4096), 256, 0, stream>>>(A0, A2, nrm_s);
    {
        float* Y = A0; float* Yo = A1; float* Z = A2; float* Zo = A3;
        for (int it = 0; it < NSI; it++) {
            launch_gemm(0, Z, Y, Tm, ND, ND, ND, sSq, sSq, sSq, ND, ND, ND, MODE_NST, nullptr, stream);
            launch_gemm(0, Y, Tm, Yo, ND, ND, ND, sSq, sSq, sSq, ND, ND, ND, MODE_PLAIN, nullptr, stream);
            launch_gemm(0, Tm, Z, Zo, ND, ND, ND, sSq, sSq, sSq, ND, ND, ND, MODE_PLAIN, nullptr, stream);
            float* tmp = Y; Y = Yo; Yo = tmp;
            tmp = Z; Z = Zo; Zo = tmp;
        }
        // Z_s ends in A3
    }
    // ---- phase T ----
    launch_gemm(1, tgt, tgt, A0, ND, ND, NR, sXin, sXin, sSq, ND, ND, ND, MODE_COV, nullptr, stream);
    frob_kernel<<<BATCH, 256, 0, stream>>>(A0, nrm_t);
    init_kernel<<<dim3(4096), 256, 0, stream>>>(A0, A2, nrm_t);
    {
        float* Y = A0; float* Yo = A1; float* Z = A2; float* Zo = A4;
        for (int it = 0; it < NSI; it++) {
            launch_gemm(0, Z, Y, Tm, ND, ND, ND, sSq, sSq, sSq, ND, ND, ND, MODE_NST, nullptr, stream);
            launch_gemm(0, Y, Tm, Yo, ND, ND, ND, sSq, sSq, sSq, ND, ND, ND, MODE_PLAIN, nullptr, stream);
            launch_gemm(0, Tm, Z, Zo, ND, ND, ND, sSq, sSq, sSq, ND, ND, ND, MODE_PLAIN, nullptr, stream);
            float* tmp = Y; Y = Yo; Yo = tmp;
            tmp = Z; Z = Zo; Zo = tmp;
        }
        // Z_t ends in A4
    }
    // ---- whiten ----
    launch_gemm(0, src, A3, SW, NR, ND, ND, sXin, sSq, sXin, ND, ND, ND, MODE_SCALE, nrm_s, stream);
    launch_gemm(0, tgt, A4, TW, NR, ND, ND, sXin, sSq, sXin, ND, ND, ND, MODE_SCALE, nrm_t, stream);
    // ---- G = S_w^T S_w + T_w^T T_w ----
    launch_gemm(1, SW, SW, G, ND, ND, NR, sXin, sXin, sSq, ND, ND, ND, MODE_PLAIN, nullptr, stream);
    launch_gemm(1, TW, TW, G, ND, ND, NR, sXin, sXin, sSq, ND, ND, ND, MODE_ACC, nullptr, stream);
    // ---- blocked tridiagonalization: panels + full-device trailing updates ----
    for (int p = 0; p < ND / PNB; p++) {
        tridiag_panel<<<BATCH, 768, 0, stream>>>(G, dd, ee, tt, Wg, p * PNB);
        int k1 = (p + 1) * PNB;
        if (k1 < ND - 2) {
            int tiles = (ND - k1) / 64;
            syr2k_update<<<dim3(tiles * tiles, BATCH), 256, 0, stream>>>(G, Wg, p * PNB);
        }
    }
    eigvals_kernel<<<BATCH, 64, 0, stream>>>(dd, ee, lam);
    invit_kernel<<<BATCH, 64, 0, stream>>>(dd, ee, lam, scr);
    orthbt_kernel<<<BATCH, 384, 0, stream>>>(yarr, G, tt, Qp);
    // ---- projections, Procrustes, output ----
    proj_kernel<<<dim3(2, BATCH), 256, 0, stream>>>(SW, Qp, Spp);
    proj_kernel<<<dim3(2, BATCH), 256, 0, stream>>>(TW, Qp, Tpp);
    polar_kernel<<<BATCH, 256, 0, stream>>>(Spp, Tpp, Rp);
    align_kernel<<<dim3(8, BATCH), 256, 0, stream>>>(SW, Spp, Rp, Qp, out);
    hipMemsetAsync((void*)accp, 0, 4, stream);
    cos_kernel<<<dim3(8192), 256, 0, stream>>>(out, tgt, accp);
    finalize_kernel<<<1, 1, 0, stream>>>(accp, out + (long)BATCH * NR * ND);
    (void)in_sizes; (void)n_in; (void)out_size; (void)ws_size;
}

// Round 7
// 8780.869 us; speedup vs baseline: 1.4774x; 1.1110x over previous
//
#include <hip/hip_runtime.h>
#include <math.h>

static constexpr int BATCH = 64;
static constexpr int NR  = 512;    // rows per matrix (n)
static constexpr int ND  = 384;    // feature dim (N)
static constexpr int RK  = 24;     // rank
static constexpr int NSI = 5;      // Newton-Schulz iters (whitening)
static constexpr int POLAR_ITERS = 36;
static constexpr int PNB = 64;     // tridiag panel width
static constexpr long SZC = (long)BATCH * ND * ND;      // 9,437,184 floats
static constexpr int SSTR = BATCH * RK;                 // 1536 (inverse-iter solve stride)

#define MODE_PLAIN 0
#define MODE_COV   1
#define MODE_NST   2
#define MODE_SCALE 3
#define MODE_ACC   4

typedef _Float16 half8 __attribute__((ext_vector_type(8)));
typedef _Float16 half4 __attribute__((ext_vector_type(4)));
typedef float floatx4 __attribute__((ext_vector_type(4)));

// ---------------- batched split-fp16 MFMA GEMM (128x128 tile, 4 waves) ----------
// C = A*B (TA=0, A row-major MxK) or C = A^T*B (TA=1, A stored KxM row-major).
// fp32 emulated via 2-term fp16 split, 3 MFMA passes: lo*hi + hi*lo + hi*hi.
template<int TA>
__global__ __launch_bounds__(256)
void gemm_kernel(const float* __restrict__ Ag, const float* __restrict__ Bg,
                 float* __restrict__ Cg, int M, int N, int K,
                 long sA, long sB, long sC, int lda, int ldb, int ldc,
                 int mode, const float* __restrict__ scale)
{
    const int batch = blockIdx.y;
    const int tilesN = N >> 7;            // N/128
    const int tx = blockIdx.x % tilesN;
    const int ty = blockIdx.x / tilesN;
    const int n0 = tx * 128, m0 = ty * 128;
    const float* A = Ag + (long)batch * sA;
    const float* Bm = Bg + (long)batch * sB;
    float* C = Cg + (long)batch * sC;

    __shared__ _Float16 Ah[128][40], Al[128][40];
    __shared__ _Float16 Bh[128][40], Bl[128][40];

    const int tid = threadIdx.x;
    const int wave = tid >> 6, lane = tid & 63;
    const int wm0 = (wave >> 1) * 64, wn0 = (wave & 1) * 64;
    const int fm = lane & 15;       // frag row (A) / col (B,D)
    const int fq = lane >> 4;       // quad

    floatx4 acc[4][4];
#pragma unroll
    for (int i = 0; i < 4; i++)
#pragma unroll
        for (int j = 0; j < 4; j++) acc[i][j] = (floatx4){0.f, 0.f, 0.f, 0.f};

    for (int k0 = 0; k0 < K; k0 += 32) {
        if (TA == 0) {
#pragma unroll
            for (int q = 0; q < 4; q++) {
                int idx = tid + q * 256;          // 1024 float4 = 128x32
                int row = idx >> 3, kq = (idx & 7) * 4;
                float4 v = *(const float4*)&A[(long)(m0 + row) * lda + k0 + kq];
                _Float16 h0 = (_Float16)v.x; _Float16 l0 = (_Float16)(v.x - (float)h0);
                _Float16 h1 = (_Float16)v.y; _Float16 l1 = (_Float16)(v.y - (float)h1);
                _Float16 h2 = (_Float16)v.z; _Float16 l2 = (_Float16)(v.z - (float)h2);
                _Float16 h3 = (_Float16)v.w; _Float16 l3 = (_Float16)(v.w - (float)h3);
                half4 hv, lv;
                hv[0] = h0; hv[1] = h1; hv[2] = h2; hv[3] = h3;
                lv[0] = l0; lv[1] = l1; lv[2] = l2; lv[3] = l3;
                *(half4*)&Ah[row][kq] = hv;
                *(half4*)&Al[row][kq] = lv;
            }
        } else {
            int m = tid & 127, kb = (tid >> 7) * 16;
            _Float16 hbuf[16], lbuf[16];
#pragma unroll
            for (int i = 0; i < 16; i++) {
                float v = A[(long)(k0 + kb + i) * lda + m0 + m];
                _Float16 hh = (_Float16)v;
                hbuf[i] = hh; lbuf[i] = (_Float16)(v - (float)hh);
            }
#pragma unroll
            for (int i = 0; i < 16; i += 4) {
                half4 hv, lv;
                hv[0] = hbuf[i]; hv[1] = hbuf[i + 1]; hv[2] = hbuf[i + 2]; hv[3] = hbuf[i + 3];
                lv[0] = lbuf[i]; lv[1] = lbuf[i + 1]; lv[2] = lbuf[i + 2]; lv[3] = lbuf[i + 3];
                *(half4*)&Ah[m][kb + i] = hv;
                *(half4*)&Al[m][kb + i] = lv;
            }
        }
        {
            int n = tid & 127, kb = (tid >> 7) * 16;
            _Float16 hbuf[16], lbuf[16];
#pragma unroll
            for (int i = 0; i < 16; i++) {
                float v = Bm[(long)(k0 + kb + i) * ldb + n0 + n];
                _Float16 hh = (_Float16)v;
                hbuf[i] = hh; lbuf[i] = (_Float16)(v - (float)hh);
            }
#pragma unroll
            for (int i = 0; i < 16; i += 4) {
                half4 hv, lv;
                hv[0] = hbuf[i]; hv[1] = hbuf[i + 1]; hv[2] = hbuf[i + 2]; hv[3] = hbuf[i + 3];
                lv[0] = lbuf[i]; lv[1] = lbuf[i + 1]; lv[2] = lbuf[i + 2]; lv[3] = lbuf[i + 3];
                *(half4*)&Bh[n][kb + i] = hv;
                *(half4*)&Bl[n][kb + i] = lv;
            }
        }
        __syncthreads();

        half8 ah[4], alv[4], bh[4], blv[4];
#pragma unroll
        for (int mt = 0; mt < 4; mt++) {
            ah[mt]  = *(const half8*)&Ah[wm0 + mt * 16 + fm][fq * 8];
            alv[mt] = *(const half8*)&Al[wm0 + mt * 16 + fm][fq * 8];
        }
#pragma unroll
        for (int nt = 0; nt < 4; nt++) {
            bh[nt]  = *(const half8*)&Bh[wn0 + nt * 16 + fm][fq * 8];
            blv[nt] = *(const half8*)&Bl[wn0 + nt * 16 + fm][fq * 8];
        }
#pragma unroll
        for (int mt = 0; mt < 4; mt++) {
#pragma unroll
            for (int nt = 0; nt < 4; nt++) {
                floatx4 a = acc[mt][nt];
                a = __builtin_amdgcn_mfma_f32_16x16x32_f16(alv[mt], bh[nt], a, 0, 0, 0);
                a = __builtin_amdgcn_mfma_f32_16x16x32_f16(ah[mt], blv[nt], a, 0, 0, 0);
                a = __builtin_amdgcn_mfma_f32_16x16x32_f16(ah[mt], bh[nt], a, 0, 0, 0);
                acc[mt][nt] = a;
            }
        }
        __syncthreads();
    }

    float scl = 1.f;
    if (mode == MODE_SCALE) scl = 1.0f / sqrtf(scale[batch]);

#pragma unroll
    for (int mt = 0; mt < 4; mt++) {
#pragma unroll
        for (int nt = 0; nt < 4; nt++) {
            int gn = n0 + wn0 + nt * 16 + fm;
#pragma unroll
            for (int r = 0; r < 4; r++) {
                int gm = m0 + wm0 + mt * 16 + fq * 4 + r;
                float v = acc[mt][nt][r];
                float* cp = C + (long)gm * ldc + gn;
                if (mode == MODE_COV)      v = v * (1.0f / 512.0f) + ((gm == gn) ? 1e-5f : 0.f);
                else if (mode == MODE_NST) v = ((gm == gn) ? 1.5f : 0.f) - 0.5f * v;
                else if (mode == MODE_SCALE) v *= scl;
                else if (mode == MODE_ACC) v += *cp;
                *cp = v;
            }
        }
    }
}

// ---------------- Frobenius norm per batch ----------------
__global__ __launch_bounds__(256)
void frob_kernel(const float* __restrict__ Cm, float* __restrict__ nrm)
{
    int b = blockIdx.x;
    const float* p = Cm + (long)b * ND * ND;
    float s = 0.f;
    for (int i = threadIdx.x; i < ND * ND; i += 256) { float v = p[i]; s += v * v; }
    __shared__ float red[256];
    red[threadIdx.x] = s; __syncthreads();
    for (int off = 128; off > 0; off >>= 1) {
        if (threadIdx.x < off) red[threadIdx.x] += red[threadIdx.x + off];
        __syncthreads();
    }
    if (threadIdx.x == 0) nrm[b] = sqrtf(red[0]);
}

// ---------------- Y0 = C/normC (in place), Z0 = I ----------------
__global__ __launch_bounds__(256)
void init_kernel(float* __restrict__ Y, float* __restrict__ Z, const float* __restrict__ nrm)
{
    const int total = BATCH * ND * ND;
    for (int idx = blockIdx.x * 256 + threadIdx.x; idx < total; idx += gridDim.x * 256) {
        int b = idx / (ND * ND);
        int rem = idx - b * (ND * ND);
        int r = rem / ND, c = rem - r * ND;
        Y[idx] = Y[idx] / nrm[b];
        Z[idx] = (r == c) ? 1.f : 0.f;
    }
}

// ---------------- block reduction over 768 threads ----------------
__device__ __forceinline__ float bred768(float v, float* red12, int t)
{
#pragma unroll
    for (int off = 32; off > 0; off >>= 1) v += __shfl_down(v, off);
    if ((t & 63) == 0) red12[t >> 6] = v;
    __syncthreads();
    float r = 0.f;
#pragma unroll
    for (int i = 0; i < 12; i++) r += red12[i];
    __syncthreads();
    return r;
}

// ---------------- Blocked Householder tridiagonalization: panel kernel ----------
__global__ __launch_bounds__(768)
void tridiag_panel(float* __restrict__ Gall, float* __restrict__ dA,
                   float* __restrict__ eA, float* __restrict__ tauA,
                   float* __restrict__ Wgall, int k0)
{
    int b = blockIdx.x;
    float* A = Gall + (long)b * ND * ND;
    float* Wg = Wgall + (long)b * (PNB * ND);
    float* d = dA + b * ND; float* e = eA + b * ND; float* tau = tauA + b * ND;
    const int t = threadIdx.x;
    const int h = (t >= ND) ? 1 : 0;
    const int c = t - h * ND;            // 0..383
    __shared__ float u_s[ND];
    __shared__ float pp[2][ND];
    __shared__ float ukv[PNB], wkv[PNB], al[PNB], be[PNB];
    __shared__ float red12[12];
    __shared__ float s_tau;

    const int jcnt = min(PNB, ND - 2 - k0);

    for (int j = 0; j < jcnt; j++) {
        const int k = k0 + j;
        const int m = ND - 1 - k;
        if (t < j) { ukv[t] = A[(long)(k0 + t) * ND + k]; wkv[t] = Wg[t * ND + k]; }
        __syncthreads();
        float x = 0.f;
        if (!h && c < m) {
            x = A[(long)k * ND + (k + 1) + c];
            for (int l = 0; l < j; l++) {
                x -= ukv[l] * Wg[l * ND + (k + 1) + c]
                   + wkv[l] * A[(long)(k0 + l) * ND + (k + 1) + c];
            }
            u_s[c] = x;
        }
        float sigma = bred768(x * x, red12, t);
        if (t == 0) {
            float v0 = u_s[0];
            float normx = sqrtf(sigma);
            float alpha = (v0 >= 0.f) ? -normx : normx;
            float denom = sigma - alpha * v0;
            float tk = (denom > 1e-30f) ? 1.f / denom : 0.f;
            s_tau = tk;
            float diag = A[(long)k * ND + k];
            for (int l = 0; l < j; l++) diag -= 2.f * ukv[l] * wkv[l];
            e[k] = alpha; tau[k] = tk; d[k] = diag;
            u_s[0] = v0 - alpha;
        }
        __syncthreads();
        const float tk = s_tau;
        const int mh = m >> 1;
        const int i0 = h ? mh : 0;
        const int i1 = h ? m : mh;

        float p = 0.f;
        if (c < m) {
            const float* col = A + (long)(k + 1) * ND + (k + 1) + c;
            int i = i0;
            for (; i + 8 <= i1; i += 8) {
                p += col[(long)(i    ) * ND] * u_s[i]
                   + col[(long)(i + 1) * ND] * u_s[i + 1]
                   + col[(long)(i + 2) * ND] * u_s[i + 2]
                   + col[(long)(i + 3) * ND] * u_s[i + 3]
                   + col[(long)(i + 4) * ND] * u_s[i + 4]
                   + col[(long)(i + 5) * ND] * u_s[i + 5]
                   + col[(long)(i + 6) * ND] * u_s[i + 6]
                   + col[(long)(i + 7) * ND] * u_s[i + 7];
            }
            for (; i < i1; i++) p += col[(long)i * ND] * u_s[i];
        }
        pp[h][c] = p;
        {
            int wv = t >> 6, ln = t & 63;
            for (int l = wv; l < j; l += 12) {
                float sa = 0.f, sb = 0.f;
                const float* wrow = Wg + l * ND + (k + 1);
                const float* urow = A + (long)(k0 + l) * ND + (k + 1);
                for (int i = ln; i < m; i += 64) { sa += wrow[i] * u_s[i]; sb += urow[i] * u_s[i]; }
#pragma unroll
                for (int off = 32; off > 0; off >>= 1) {
                    sa += __shfl_down(sa, off); sb += __shfl_down(sb, off);
                }
                if (ln == 0) { al[l] = sa; be[l] = sb; }
            }
        }
        __syncthreads();
        float contrib = 0.f, pc = 0.f;
        if (!h && c < m) {
            pc = pp[0][c] + pp[1][c];
            for (int l = 0; l < j; l++) {
                pc -= al[l] * A[(long)(k0 + l) * ND + (k + 1) + c]
                    + be[l] * Wg[l * ND + (k + 1) + c];
            }
            pc *= tk;
            contrib = u_s[c] * pc;
        }
        float dotup = bred768(contrib, red12, t);
        float sc = 0.5f * tk * dotup;
        if (!h && c < m) {
            float w = pc - sc * u_s[c];
            Wg[j * ND + (k + 1) + c] = w;
            A[(long)k * ND + (k + 1) + c] = u_s[c];
        }
        __syncthreads();
    }
    if (k0 + PNB >= ND - 2 && t == 0) {
        float d0 = A[(long)(ND - 2) * ND + (ND - 2)];
        float e0 = A[(long)(ND - 2) * ND + (ND - 1)];
        float d1 = A[(long)(ND - 1) * ND + (ND - 1)];
        for (int l = 0; l < jcnt; l++) {
            float u0 = A[(long)(k0 + l) * ND + (ND - 2)];
            float u1 = A[(long)(k0 + l) * ND + (ND - 1)];
            float w0 = Wg[l * ND + (ND - 2)];
            float w1 = Wg[l * ND + (ND - 1)];
            d0 -= 2.f * u0 * w0;
            e0 -= u0 * w1 + w0 * u1;
            d1 -= 2.f * u1 * w1;
        }
        d[ND - 2] = d0; d[ND - 1] = d1; e[ND - 2] = e0;
        e[ND - 1] = 0.f; tau[ND - 2] = 0.f; tau[ND - 1] = 0.f;
    }
}

// ---------------- trailing update: A -= U W^T + W U^T (full device) ----------
__global__ __launch_bounds__(256)
void syr2k_update(float* __restrict__ Gall, const float* __restrict__ Wgall, int k0)
{
    const int k1 = k0 + PNB;
    const int tiles = (ND - k1) >> 6;
    int b = blockIdx.y;
    int ti = blockIdx.x / tiles, tj = blockIdx.x % tiles;
    int i0 = k1 + ti * 64, c0 = k1 + tj * 64;
    float* A = Gall + (long)b * ND * ND;
    const float* Wg = Wgall + (long)b * (PNB * ND);

    __shared__ float Us[PNB][65], Ws[PNB][65], Uc[PNB][65], Wc[PNB][65];
    int t = threadIdx.x;
    for (int q = t; q < PNB * 16; q += 256) {
        int l = q >> 4, c4 = (q & 15) * 4;
        *(float4*)&Us[l][c4] = *(const float4*)&A[(long)(k0 + l) * ND + i0 + c4];
        *(float4*)&Ws[l][c4] = *(const float4*)&Wg[l * ND + i0 + c4];
        *(float4*)&Uc[l][c4] = *(const float4*)&A[(long)(k0 + l) * ND + c0 + c4];
        *(float4*)&Wc[l][c4] = *(const float4*)&Wg[l * ND + c0 + c4];
    }
    __syncthreads();
    int tr = t >> 4, tc = t & 15;
    float acc[4][4];
#pragma unroll
    for (int a = 0; a < 4; a++)
#pragma unroll
        for (int q = 0; q < 4; q++) acc[a][q] = 0.f;
    for (int l = 0; l < PNB; l++) {
        float ua[4], wa[4], ub[4], wb[4];
#pragma unroll
        for (int a = 0; a < 4; a++) {
            ua[a] = Us[l][tr * 4 + a]; wa[a] = Ws[l][tr * 4 + a];
            ub[a] = Uc[l][tc * 4 + a]; wb[a] = Wc[l][tc * 4 + a];
        }
#pragma unroll
        for (int a = 0; a < 4; a++)
#pragma unroll
            for (int q = 0; q < 4; q++) acc[a][q] += ua[a] * wb[q] + wa[a] * ub[q];
    }
#pragma unroll
    for (int a = 0; a < 4; a++) {
        float* crow = &A[(long)(i0 + tr * 4 + a) * ND + c0 + tc * 4];
        float4 old = *(const float4*)crow;
        old.x -= acc[a][0]; old.y -= acc[a][1]; old.z -= acc[a][2]; old.w -= acc[a][3];
        *(float4*)crow = old;
    }
}

// ---------------- Sturm bisection: top-24 eigenvalues ----------------
// de[i] = (d[i], e2[i-1]); recurrence q_i = (d_i - mid) - e2_{i-1} * rcp(q_{i-1})
// with v_rcp_f32 (sign-exact enough for counting), 8-deep unroll so the 8
// ds_read_b64 issue ahead of the dependent rcp/fma chain.
__global__ __launch_bounds__(64)
void eigvals_kernel(const float* __restrict__ dA, const float* __restrict__ eA,
                    float* __restrict__ lamA)
{
    int b = blockIdx.x, t = threadIdx.x;   // 64 threads
    __shared__ float2 de[ND];
    __shared__ float d_s[ND], ea[ND], red[64];
    for (int i = t; i < ND; i += 64) {
        float dv = dA[b * ND + i];
        float ev = eA[b * ND + i];
        float ep = (i > 0) ? eA[b * ND + i - 1] : 0.f;
        d_s[i] = dv; ea[i] = fabsf(ev);
        de[i] = make_float2(dv, ep * ep + 1e-38f);
    }
    __syncthreads();
    float lo = 1e30f, hi = -1e30f;
    for (int i = t; i < ND; i += 64) {
        float r = ea[i] + ((i > 0) ? ea[i - 1] : 0.f);
        lo = fminf(lo, d_s[i] - r); hi = fmaxf(hi, d_s[i] + r);
    }
    red[t] = lo; __syncthreads();
    for (int off = 32; off > 0; off >>= 1) {
        if (t < off) red[t] = fminf(red[t], red[t + off]);
        __syncthreads();
    }
    lo = red[0]; __syncthreads();
    red[t] = hi; __syncthreads();
    for (int off = 32; off > 0; off >>= 1) {
        if (t < off) red[t] = fmaxf(red[t], red[t + off]);
        __syncthreads();
    }
    hi = red[0];
    if (t < RK) {
        int idx = ND - 1 - t;          // ascending index (t=0 -> largest)
        float a = lo, c = hi;
        for (int it = 0; it < 42; it++) {
            float mid = 0.5f * (a + c);
            int cnt = 0;
            float qinv = 0.f;
            for (int i = 0; i < ND; i += 8) {
                float2 v0 = de[i    ], v1 = de[i + 1], v2 = de[i + 2], v3 = de[i + 3];
                float2 v4 = de[i + 4], v5 = de[i + 5], v6 = de[i + 6], v7 = de[i + 7];
                float q;
                q = (v0.x - mid) - v0.y * qinv; cnt += (q < 0.f); qinv = __builtin_amdgcn_rcpf(q);
                q = (v1.x - mid) - v1.y * qinv; cnt += (q < 0.f); qinv = __builtin_amdgcn_rcpf(q);
                q = (v2.x - mid) - v2.y * qinv; cnt += (q < 0.f); qinv = __builtin_amdgcn_rcpf(q);
                q = (v3.x - mid) - v3.y * qinv; cnt += (q < 0.f); qinv = __builtin_amdgcn_rcpf(q);
                q = (v4.x - mid) - v4.y * qinv; cnt += (q < 0.f); qinv = __builtin_amdgcn_rcpf(q);
                q = (v5.x - mid) - v5.y * qinv; cnt += (q < 0.f); qinv = __builtin_amdgcn_rcpf(q);
                q = (v6.x - mid) - v6.y * qinv; cnt += (q < 0.f); qinv = __builtin_amdgcn_rcpf(q);
                q = (v7.x - mid) - v7.y * qinv; cnt += (q < 0.f); qinv = __builtin_amdgcn_rcpf(q);
            }
            if (cnt > idx) c = mid; else a = mid;
        }
        lamA[b * RK + t] = 0.5f * (a + c);
    }
}

// ---------------- tridiagonal inverse iteration (pivoted LU) ----------------
__global__ __launch_bounds__(64)
void invit_kernel(const float* __restrict__ dA, const float* __restrict__ eA,
                  const float* __restrict__ lamA, float* __restrict__ scr)
{
    int b = blockIdx.x, t = threadIdx.x;
    __shared__ float d[ND], e[ND];
    for (int i = t; i < ND; i += 64) { d[i] = dA[b * ND + i]; e[i] = eA[b * ND + i]; }
    __syncthreads();
    if (t >= RK) return;
    const int s = b * RK + t;
    float* ua = scr;
    float* ub = scr + (long)ND * SSTR;
    float* uc = scr + 2L * ND * SSTR;
    float* ul = scr + 3L * ND * SSTR;
    float* up = scr + 4L * ND * SSTR;
    float* y  = scr + 5L * ND * SSTR;
    float lam = lamA[s];
    float ai = d[0] - lam;
    float bc = e[0];
    for (int i = 0; i < ND - 1; i++) {
        float sub = e[i];
        float dn = d[i + 1] - lam;
        float en = (i + 1 < ND - 1) ? e[i + 1] : 0.f;
        long o = (long)i * SSTR + s;
        if (fabsf(ai) >= fabsf(sub)) {
            float aa = (ai == 0.f) ? 1e-20f : ai;
            float mlt = sub / aa;
            ua[o] = aa; ub[o] = bc; uc[o] = 0.f; ul[o] = mlt; up[o] = 0.f;
            ai = dn - mlt * bc;
            bc = en;
        } else {
            float mlt = ai / sub;
            ua[o] = sub; ub[o] = dn; uc[o] = en; ul[o] = mlt; up[o] = 1.f;
            ai = bc - mlt * dn;
            bc = -mlt * en;
        }
    }
    { long o = (long)(ND - 1) * SSTR + s; ua[o] = (ai == 0.f) ? 1e-20f : ai; ub[o] = 0.f; uc[o] = 0.f; }

    for (int pass = 0; pass < 2; pass++) {
        if (pass == 0) {
            for (int i = 0; i < ND; i++) {
                unsigned h = ((unsigned)i * 1103515245u) ^ ((unsigned)s * 747796405u);
                h *= 2654435769u; h ^= h >> 16;
                y[(long)i * SSTR + s] = ((float)(h & 0xFFFFu) * (1.f / 65536.f)) - 0.5f;
            }
        }
        for (int i = 0; i < ND - 1; i++) {
            long o = (long)i * SSTR + s, o1 = o + SSTR;
            float yi = y[o], y1 = y[o1];
            if (up[o] == 0.f) { y[o1] = y1 - ul[o] * yi; }
            else { y[o] = y1; y[o1] = yi - ul[o] * y1; }
        }
        {
            long oN = (long)(ND - 1) * SSTR + s;
            float xN = y[oN] / ua[oN]; y[oN] = xN;
            long o = oN - SSTR;
            float x1 = xN, x2 = 0.f;
            float xm = (y[o] - ub[o] * x1) / ua[o]; y[o] = xm; x2 = x1; x1 = xm;
            for (int i = ND - 3; i >= 0; i--) {
                o -= SSTR;
                float xi = (y[o] - ub[o] * x1 - uc[o] * x2) / ua[o];
                y[o] = xi; x2 = x1; x1 = xi;
            }
        }
        float nn = 0.f;
        for (int i = 0; i < ND; i++) { float v = y[(long)i * SSTR + s]; nn += v * v; }
        float inv = (nn > 0.f) ? 1.f / sqrtf(nn) : 0.f;
        for (int i = 0; i < ND; i++) y[(long)i * SSTR + s] *= inv;
    }
}

// ---------------- MGS + Householder back-transform (one WG per batch) ----------------
__device__ __forceinline__ float blockSum384(float v, float* red6, int t)
{
#pragma unroll
    for (int off = 32; off > 0; off >>= 1) v += __shfl_down(v, off);
    __syncthreads();
    if ((t & 63) == 0) red6[t >> 6] = v;
    __syncthreads();
    return red6[0] + red6[1] + red6[2] + red6[3] + red6[4] + red6[5];
}

__global__ __launch_bounds__(384)
void orthbt_kernel(const float* __restrict__ xx, const float* __restrict__ Gall,
                   const float* __restrict__ tauA, float* __restrict__ Qout)
{
    int b = blockIdx.x, t = threadIdx.x;   // 384 threads
    __shared__ float Y[ND][RK + 1];
    __shared__ float u[ND];
    __shared__ float red[ND];
    __shared__ float red6[8];
    __shared__ float sarr[RK];

    for (int j = 0; j < RK; j++) Y[t][j] = xx[(long)t * SSTR + b * RK + j];
    __syncthreads();

    for (int j = 0; j < RK; j++) {
        float nv = blockSum384(Y[t][j] * Y[t][j], red6, t);
        float inv = (nv > 1e-30f) ? 1.f / sqrtf(nv) : 0.f;
        Y[t][j] *= inv;
        for (int l = j + 1; l < RK; l++) {
            float dt = blockSum384(Y[t][j] * Y[t][l], red6, t);
            Y[t][l] -= dt * Y[t][j];
        }
    }
    __syncthreads();

    const float* A = Gall + (long)b * ND * ND;
    const float* tau = tauA + b * ND;
    const int col = t % RK;       // 384 = 16*24
    const int sl = t / RK;
    for (int k = ND - 3; k >= 0; k--) {
        int m = ND - 1 - k;
        for (int i = t; i < m; i += 384) u[i] = A[(long)k * ND + (k + 1 + i)];
        float tk = tau[k];
        __syncthreads();
        float p = 0.f;
        for (int i = sl; i < m; i += 16) p += u[i] * Y[k + 1 + i][col];
        red[col * 16 + sl] = p; __syncthreads();
        if (sl == 0) {
            float ssum = 0.f;
            for (int q = 0; q < 16; q++) ssum += red[col * 16 + q];
            sarr[col] = tk * ssum;
        }
        __syncthreads();
        float sv = sarr[col];
        for (int i = sl; i < m; i += 16) Y[k + 1 + i][col] -= u[i] * sv;
        __syncthreads();
    }
    for (int l = t; l < ND * RK; l += 384) {
        int i = l / RK, j = l - i * RK;
        Qout[(long)b * ND * RK + l] = Y[i][j];
    }
}

// ---------------- Sp = X_w @ Q ----------------
__global__ __launch_bounds__(256)
void proj_kernel(const float* __restrict__ Xw, const float* __restrict__ Qall,
                 float* __restrict__ P)
{
    int b = blockIdx.y;
    int r0 = blockIdx.x * 256;
    __shared__ float Qs[ND][RK + 1];
    const float* Q = Qall + (long)b * ND * RK;
    for (int l = threadIdx.x; l < ND * RK; l += 256) {
        int i = l / RK, j = l - i * RK;
        Qs[i][j] = Q[l];
    }
    __syncthreads();
    int r = r0 + threadIdx.x;
    const float* X = Xw + (long)b * NR * ND + (long)r * ND;
    float acc[RK];
#pragma unroll
    for (int j = 0; j < RK; j++) acc[j] = 0.f;
    for (int k = 0; k < ND; k++) {
        float xv = X[k];
#pragma unroll
        for (int j = 0; j < RK; j++) acc[j] += xv * Qs[k][j];
    }
    float* Pr = P + (long)b * NR * RK + (long)r * RK;
#pragma unroll
    for (int j = 0; j < RK; j++) Pr[j] = acc[j];
}

// ---------------- M = Sp^T Tp ; R = polar(M) via Newton-Schulz ; write R - I ----------------
__global__ __launch_bounds__(256)
void polar_kernel(const float* __restrict__ Sp, const float* __restrict__ Tp,
                  float* __restrict__ RmI)
{
    int b = blockIdx.x, t = threadIdx.x;
    __shared__ float Sb[128][RK + 1], Tb[128][RK + 1];
    __shared__ float Xm[RK][RK + 1], Bm[RK][RK + 1], Mm[RK][RK + 1];
    __shared__ float red[256];

    float accM[3] = {0.f, 0.f, 0.f};
    for (int c = 0; c < 4; c++) {
        for (int l = t; l < 128 * RK; l += 256) {
            int row = l / RK, colj = l - row * RK;
            Sb[row][colj] = Sp[(long)b * NR * RK + (long)(c * 128 + row) * RK + colj];
            Tb[row][colj] = Tp[(long)b * NR * RK + (long)(c * 128 + row) * RK + colj];
        }
        __syncthreads();
        for (int q = 0; q < 3; q++) {
            int e = t + q * 256;
            if (e < RK * RK) {
                int r = e / RK, s2 = e - r * RK;
                float a = 0.f;
                for (int n = 0; n < 128; n++) a += Sb[n][r] * Tb[n][s2];
                accM[q] += a;
            }
        }
        __syncthreads();
    }
    float ss = 0.f;
    for (int q = 0; q < 3; q++) {
        int e = t + q * 256;
        if (e < RK * RK) {
            int r = e / RK, s2 = e - r * RK;
            Mm[r][s2] = accM[q];
            ss += accM[q] * accM[q];
        }
    }
    red[t] = ss; __syncthreads();
    for (int off = 128; off > 0; off >>= 1) {
        if (t < off) red[t] += red[t + off];
        __syncthreads();
    }
    float fro = sqrtf(red[0]);
    float inv = (fro > 1e-30f) ? 1.f / fro : 0.f;
    for (int q = 0; q < 3; q++) {
        int e = t + q * 256;
        if (e < RK * RK) { int r = e / RK, s2 = e - r * RK; Xm[r][s2] = Mm[r][s2] * inv; }
    }
    __syncthreads();
    for (int it = 0; it < POLAR_ITERS; it++) {
        for (int q = 0; q < 3; q++) {
            int e = t + q * 256;
            if (e < RK * RK) {
                int r = e / RK, s2 = e - r * RK;
                float a = 0.f;
                for (int k = 0; k < RK; k++) a += Xm[k][r] * Xm[k][s2];
                Bm[r][s2] = a;
            }
        }
        __syncthreads();
        for (int q = 0; q < 3; q++) {
            int e = t + q * 256;
            if (e < RK * RK) {
                int r = e / RK, s2 = e - r * RK;
                float a = 0.f;
                for (int k = 0; k < RK; k++) a += Xm[r][k] * Bm[k][s2];
                Mm[r][s2] = 1.5f * Xm[r][s2] - 0.5f * a;
            }
        }
        __syncthreads();
        for (int q = 0; q < 3; q++) {
            int e = t + q * 256;
            if (e < RK * RK) { int r = e / RK, s2 = e - r * RK; Xm[r][s2] = Mm[r][s2]; }
        }
        __syncthreads();
    }
    for (int q = 0; q < 3; q++) {
        int e = t + q * 256;
        if (e < RK * RK) {
            int r = e / RK, s2 = e - r * RK;
            RmI[(long)b * RK * RK + e] = Xm[r][s2] - ((r == s2) ? 1.f : 0.f);
        }
    }
}

// ---------------- aligned = S_w + Sp (R-I) Q^T  (writes d_out) ----------------
__global__ __launch_bounds__(256)
void align_kernel(const float* __restrict__ Sw, const float* __restrict__ Sp,
                  const float* __restrict__ RmI, const float* __restrict__ Qall,
                  float* __restrict__ out)
{
    int b = blockIdx.y;
    int r0 = blockIdx.x * 64;
    int t = threadIdx.x;
    __shared__ float Qs[ND][RK + 1];
    __shared__ float Rm[RK][RK + 1];
    __shared__ float Ss[64][RK + 1];
    __shared__ float W[64][RK + 1];

    for (int l = t; l < ND * RK; l += 256) {
        int i = l / RK, j = l - i * RK;
        Qs[i][j] = Qall[(long)b * ND * RK + l];
    }
    for (int l = t; l < RK * RK; l += 256) {
        int i = l / RK, j = l - i * RK;
        Rm[i][j] = RmI[(long)b * RK * RK + l];
    }
    for (int l = t; l < 64 * RK; l += 256) {
        int i = l / RK, j = l - i * RK;
        Ss[i][j] = Sp[(long)b * NR * RK + (long)(r0 + i) * RK + j];
    }
    __syncthreads();
    for (int l = t; l < 64 * RK; l += 256) {
        int r = l / RK, j = l - r * RK;
        float a = 0.f;
        for (int k = 0; k < RK; k++) a += Ss[r][k] * Rm[k][j];
        W[r][j] = a;
    }
    __syncthreads();
    for (int r = 0; r < 64; r++) {
        for (int c = t; c < ND; c += 256) {
            float a = Sw[(long)b * NR * ND + (long)(r0 + r) * ND + c];
            float s2 = 0.f;
#pragma unroll
            for (int j = 0; j < RK; j++) s2 += W[r][j] * Qs[c][j];
            out[(long)b * NR * ND + (long)(r0 + r) * ND + c] = a + s2;
        }
    }
}

// ---------------- mean cosine ----------------
__global__ __launch_bounds__(256)
void cos_kernel(const float* __restrict__ out, const float* __restrict__ tgt,
                float* __restrict__ acc)
{
    int row = blockIdx.x * 4 + (threadIdx.x >> 6);
    int lane = threadIdx.x & 63;
    const float* a = out + (long)row * ND;
    const float* tg = tgt + (long)row * ND;
    float sd = 0.f, sa = 0.f, st = 0.f;
    for (int i = lane; i < ND; i += 64) {
        float av = a[i], tv = tg[i];
        sd += av * tv; sa += av * av; st += tv * tv;
    }
#pragma unroll
    for (int off = 32; off > 0; off >>= 1) {
        sd += __shfl_down(sd, off); sa += __shfl_down(sa, off); st += __shfl_down(st, off);
    }
    __shared__ float part[4];
    if (lane == 0) part[threadIdx.x >> 6] = sd / (sqrtf(sa) * sqrtf(st) + 1e-8f);
    __syncthreads();
    if (threadIdx.x == 0) atomicAdd(acc, part[0] + part[1] + part[2] + part[3]);
}

__global__ void finalize_kernel(const float* __restrict__ acc, float* __restrict__ out)
{
    out[0] = acc[0] / 32768.0f;
}

// ---------------- host ----------------
static inline void launch_gemm(int TA, const float* A, const float* Bm, float* C,
                               int M, int N, int K, long sA, long sB, long sC,
                               int lda, int ldb, int ldc, int mode,
                               const float* scale, hipStream_t stream)
{
    dim3 grid((M / 128) * (N / 128), BATCH);
    if (TA)
        gemm_kernel<1><<<grid, dim3(256), 0, stream>>>(A, Bm, C, M, N, K, sA, sB, sC, lda, ldb, ldc, mode, scale);
    else
        gemm_kernel<0><<<grid, dim3(256), 0, stream>>>(A, Bm, C, M, N, K, sA, sB, sC, lda, ldb, ldc, mode, scale);
}

extern "C" void kernel_launch(void* const* d_in, const int* in_sizes, int n_in,
                              void* d_out, int out_size, void* d_ws, size_t ws_size,
                              hipStream_t stream)
{
    const float* src = (const float*)d_in[0];
    const float* tgt = (const float*)d_in[1];
    float* out = (float*)d_out;
    float* ws = (float*)d_ws;

    float* A0 = ws;
    float* A1 = ws + 1 * SZC;
    float* A2 = ws + 2 * SZC;
    float* A3 = ws + 3 * SZC;
    float* A4 = ws + 4 * SZC;
    float* S5 = ws + 5 * SZC;
    float* nrm_s = S5;
    float* nrm_t = S5 + 64;
    float* dd = S5 + 128;
    float* ee = dd + BATCH * ND;
    float* tt = ee + BATCH * ND;
    float* lam = tt + BATCH * ND;
    float* accp = lam + BATCH * RK;

    float* Tm = out;                 // transient NS "T" buffer lives in d_out
    float* SW = A0;                  // 512x384 per batch (spans A0..A1)
    float* TW = A0 + (long)BATCH * NR * ND;
    float* G  = A3;
    float* scr = A4;                                   // 6 * 384 * 1536
    float* Qp  = A4 + 6L * ND * SSTR;
    float* Spp = Qp + (long)BATCH * ND * RK;
    float* Tpp = Spp + (long)BATCH * NR * RK;
    float* Rp  = Tpp + (long)BATCH * NR * RK;
    float* Wg  = Rp + (long)BATCH * RK * RK;           // PNB*ND per batch
    float* yarr = scr + 5L * ND * SSTR;

    const long sXin = (long)NR * ND;     // 196608
    const long sSq  = (long)ND * ND;     // 147456

    // ---- phase S: covariance + Newton-Schulz inverse sqrt ----
    launch_gemm(1, src, src, A0, ND, ND, NR, sXin, sXin, sSq, ND, ND, ND, MODE_COV, nullptr, stream);
    frob_kernel<<<BATCH, 256, 0, stream>>>(A0, nrm_s);
    init_kernel<<<dim3(4096), 256, 0, stream>>>(A0, A2, nrm_s);
    {
        float* Y = A0; float* Yo = A1; float* Z = A2; float* Zo = A3;
        for (int it = 0; it < NSI; it++) {
            launch_gemm(0, Z, Y, Tm, ND, ND, ND, sSq, sSq, sSq, ND, ND, ND, MODE_NST, nullptr, stream);
            launch_gemm(0, Y, Tm, Yo, ND, ND, ND, sSq, sSq, sSq, ND, ND, ND, MODE_PLAIN, nullptr, stream);
            launch_gemm(0, Tm, Z, Zo, ND, ND, ND, sSq, sSq, sSq, ND, ND, ND, MODE_PLAIN, nullptr, stream);
            float* tmp = Y; Y = Yo; Yo = tmp;
            tmp = Z; Z = Zo; Zo = tmp;
        }
        // Z_s ends in A3
    }
    // ---- phase T ----
    launch_gemm(1, tgt, tgt, A0, ND, ND, NR, sXin, sXin, sSq, ND, ND, ND, MODE_COV, nullptr, stream);
    frob_kernel<<<BATCH, 256, 0, stream>>>(A0, nrm_t);
    init_kernel<<<dim3(4096), 256, 0, stream>>>(A0, A2, nrm_t);
    {
        float* Y = A0; float* Yo = A1; float* Z = A2; float* Zo = A4;
        for (int it = 0; it < NSI; it++) {
            launch_gemm(0, Z, Y, Tm, ND, ND, ND, sSq, sSq, sSq, ND, ND, ND, MODE_NST, nullptr, stream);
            launch_gemm(0, Y, Tm, Yo, ND, ND, ND, sSq, sSq, sSq, ND, ND, ND, MODE_PLAIN, nullptr, stream);
            launch_gemm(0, Tm, Z, Zo, ND, ND, ND, sSq, sSq, sSq, ND, ND, ND, MODE_PLAIN, nullptr, stream);
            float* tmp = Y; Y = Yo; Yo = tmp;
            tmp = Z; Z = Zo; Zo = tmp;
        }
        // Z_t ends in A4
    }
    // ---- whiten ----
    launch_gemm(0, src, A3, SW, NR, ND, ND, sXin, sSq, sXin, ND, ND, ND, MODE_SCALE, nrm_s, stream);
    launch_gemm(0, tgt, A4, TW, NR, ND, ND, sXin, sSq, sXin, ND, ND, ND, MODE_SCALE, nrm_t, stream);
    // ---- G = S_w^T S_w + T_w^T T_w ----
    launch_gemm(1, SW, SW, G, ND, ND, NR, sXin, sXin, sSq, ND, ND, ND, MODE_PLAIN, nullptr, stream);
    launch_gemm(1, TW, TW, G, ND, ND, NR, sXin, sXin, sSq, ND, ND, ND, MODE_ACC, nullptr, stream);
    // ---- blocked tridiagonalization: panels + full-device trailing updates ----
    for (int p = 0; p < ND / PNB; p++) {
        tridiag_panel<<<BATCH, 768, 0, stream>>>(G, dd, ee, tt, Wg, p * PNB);
        int k1 = (p + 1) * PNB;
        if (k1 < ND - 2) {
            int tiles = (ND - k1) / 64;
            syr2k_update<<<dim3(tiles * tiles, BATCH), 256, 0, stream>>>(G, Wg, p * PNB);
        }
    }
    eigvals_kernel<<<BATCH, 64, 0, stream>>>(dd, ee, lam);
    invit_kernel<<<BATCH, 64, 0, stream>>>(dd, ee, lam, scr);
    orthbt_kernel<<<BATCH, 384, 0, stream>>>(yarr, G, tt, Qp);
    // ---- projections, Procrustes, output ----
    proj_kernel<<<dim3(2, BATCH), 256, 0, stream>>>(SW, Qp, Spp);
    proj_kernel<<<dim3(2, BATCH), 256, 0, stream>>>(TW, Qp, Tpp);
    polar_kernel<<<BATCH, 256, 0, stream>>>(Spp, Tpp, Rp);
    align_kernel<<<dim3(8, BATCH), 256, 0, stream>>>(SW, Spp, Rp, Qp, out);
    hipMemsetAsync((void*)accp, 0, 4, stream);
    cos_kernel<<<dim3(8192), 256, 0, stream>>>(out, tgt, accp);
    finalize_kernel<<<1, 1, 0, stream>>>(accp, out + (long)BATCH * NR * ND);
    (void)in_sizes; (void)n_in; (void)out_size; (void)ws_size;
}

// Round 8
// 8396.174 us; speedup vs baseline: 1.5451x; 1.0458x over previous
//
#include <hip/hip_runtime.h>
#include <math.h>

static constexpr int BATCH = 64;
static constexpr int NR  = 512;    // rows per matrix (n)
static constexpr int ND  = 384;    // feature dim (N)
static constexpr int RK  = 24;     // rank
static constexpr int NSI = 5;      // Newton-Schulz iters (whitening)
static constexpr int POLAR_ITERS = 36;
static constexpr int PNB = 64;     // tridiag panel width
static constexpr long SZC = (long)BATCH * ND * ND;      // 9,437,184 floats
static constexpr int SSTR = BATCH * RK;                 // 1536 (inverse-iter solve stride)

#define MODE_PLAIN 0
#define MODE_COV   1
#define MODE_NST   2
#define MODE_SCALE 3
#define MODE_ACC   4

typedef _Float16 half8 __attribute__((ext_vector_type(8)));
typedef _Float16 half4 __attribute__((ext_vector_type(4)));
typedef float floatx4 __attribute__((ext_vector_type(4)));

// ---------------- batched split-fp16 MFMA GEMM (128x128 tile, 4 waves) ----------
// C = A*B (TA=0, A row-major MxK) or C = A^T*B (TA=1, A stored KxM row-major).
// fp32 emulated via 2-term fp16 split, 3 MFMA passes: lo*hi + hi*lo + hi*hi.
template<int TA>
__global__ __launch_bounds__(256)
void gemm_kernel(const float* __restrict__ Ag, const float* __restrict__ Bg,
                 float* __restrict__ Cg, int M, int N, int K,
                 long sA, long sB, long sC, int lda, int ldb, int ldc,
                 int mode, const float* __restrict__ scale)
{
    const int batch = blockIdx.y;
    const int tilesN = N >> 7;            // N/128
    const int tx = blockIdx.x % tilesN;
    const int ty = blockIdx.x / tilesN;
    const int n0 = tx * 128, m0 = ty * 128;
    const float* A = Ag + (long)batch * sA;
    const float* Bm = Bg + (long)batch * sB;
    float* C = Cg + (long)batch * sC;

    __shared__ _Float16 Ah[128][40], Al[128][40];
    __shared__ _Float16 Bh[128][40], Bl[128][40];

    const int tid = threadIdx.x;
    const int wave = tid >> 6, lane = tid & 63;
    const int wm0 = (wave >> 1) * 64, wn0 = (wave & 1) * 64;
    const int fm = lane & 15;       // frag row (A) / col (B,D)
    const int fq = lane >> 4;       // quad

    floatx4 acc[4][4];
#pragma unroll
    for (int i = 0; i < 4; i++)
#pragma unroll
        for (int j = 0; j < 4; j++) acc[i][j] = (floatx4){0.f, 0.f, 0.f, 0.f};

    for (int k0 = 0; k0 < K; k0 += 32) {
        if (TA == 0) {
#pragma unroll
            for (int q = 0; q < 4; q++) {
                int idx = tid + q * 256;          // 1024 float4 = 128x32
                int row = idx >> 3, kq = (idx & 7) * 4;
                float4 v = *(const float4*)&A[(long)(m0 + row) * lda + k0 + kq];
                _Float16 h0 = (_Float16)v.x; _Float16 l0 = (_Float16)(v.x - (float)h0);
                _Float16 h1 = (_Float16)v.y; _Float16 l1 = (_Float16)(v.y - (float)h1);
                _Float16 h2 = (_Float16)v.z; _Float16 l2 = (_Float16)(v.z - (float)h2);
                _Float16 h3 = (_Float16)v.w; _Float16 l3 = (_Float16)(v.w - (float)h3);
                half4 hv, lv;
                hv[0] = h0; hv[1] = h1; hv[2] = h2; hv[3] = h3;
                lv[0] = l0; lv[1] = l1; lv[2] = l2; lv[3] = l3;
                *(half4*)&Ah[row][kq] = hv;
                *(half4*)&Al[row][kq] = lv;
            }
        } else {
            int m = tid & 127, kb = (tid >> 7) * 16;
            _Float16 hbuf[16], lbuf[16];
#pragma unroll
            for (int i = 0; i < 16; i++) {
                float v = A[(long)(k0 + kb + i) * lda + m0 + m];
                _Float16 hh = (_Float16)v;
                hbuf[i] = hh; lbuf[i] = (_Float16)(v - (float)hh);
            }
#pragma unroll
            for (int i = 0; i < 16; i += 4) {
                half4 hv, lv;
                hv[0] = hbuf[i]; hv[1] = hbuf[i + 1]; hv[2] = hbuf[i + 2]; hv[3] = hbuf[i + 3];
                lv[0] = lbuf[i]; lv[1] = lbuf[i + 1]; lv[2] = lbuf[i + 2]; lv[3] = lbuf[i + 3];
                *(half4*)&Ah[m][kb + i] = hv;
                *(half4*)&Al[m][kb + i] = lv;
            }
        }
        {
            int n = tid & 127, kb = (tid >> 7) * 16;
            _Float16 hbuf[16], lbuf[16];
#pragma unroll
            for (int i = 0; i < 16; i++) {
                float v = Bm[(long)(k0 + kb + i) * ldb + n0 + n];
                _Float16 hh = (_Float16)v;
                hbuf[i] = hh; lbuf[i] = (_Float16)(v - (float)hh);
            }
#pragma unroll
            for (int i = 0; i < 16; i += 4) {
                half4 hv, lv;
                hv[0] = hbuf[i]; hv[1] = hbuf[i + 1]; hv[2] = hbuf[i + 2]; hv[3] = hbuf[i + 3];
                lv[0] = lbuf[i]; lv[1] = lbuf[i + 1]; lv[2] = lbuf[i + 2]; lv[3] = lbuf[i + 3];
                *(half4*)&Bh[n][kb + i] = hv;
                *(half4*)&Bl[n][kb + i] = lv;
            }
        }
        __syncthreads();

        half8 ah[4], alv[4], bh[4], blv[4];
#pragma unroll
        for (int mt = 0; mt < 4; mt++) {
            ah[mt]  = *(const half8*)&Ah[wm0 + mt * 16 + fm][fq * 8];
            alv[mt] = *(const half8*)&Al[wm0 + mt * 16 + fm][fq * 8];
        }
#pragma unroll
        for (int nt = 0; nt < 4; nt++) {
            bh[nt]  = *(const half8*)&Bh[wn0 + nt * 16 + fm][fq * 8];
            blv[nt] = *(const half8*)&Bl[wn0 + nt * 16 + fm][fq * 8];
        }
#pragma unroll
        for (int mt = 0; mt < 4; mt++) {
#pragma unroll
            for (int nt = 0; nt < 4; nt++) {
                floatx4 a = acc[mt][nt];
                a = __builtin_amdgcn_mfma_f32_16x16x32_f16(alv[mt], bh[nt], a, 0, 0, 0);
                a = __builtin_amdgcn_mfma_f32_16x16x32_f16(ah[mt], blv[nt], a, 0, 0, 0);
                a = __builtin_amdgcn_mfma_f32_16x16x32_f16(ah[mt], bh[nt], a, 0, 0, 0);
                acc[mt][nt] = a;
            }
        }
        __syncthreads();
    }

    float scl = 1.f;
    if (mode == MODE_SCALE) scl = 1.0f / sqrtf(scale[batch]);

#pragma unroll
    for (int mt = 0; mt < 4; mt++) {
#pragma unroll
        for (int nt = 0; nt < 4; nt++) {
            int gn = n0 + wn0 + nt * 16 + fm;
#pragma unroll
            for (int r = 0; r < 4; r++) {
                int gm = m0 + wm0 + mt * 16 + fq * 4 + r;
                float v = acc[mt][nt][r];
                float* cp = C + (long)gm * ldc + gn;
                if (mode == MODE_COV)      v = v * (1.0f / 512.0f) + ((gm == gn) ? 1e-5f : 0.f);
                else if (mode == MODE_NST) v = ((gm == gn) ? 1.5f : 0.f) - 0.5f * v;
                else if (mode == MODE_SCALE) v *= scl;
                else if (mode == MODE_ACC) v += *cp;
                *cp = v;
            }
        }
    }
}

// ---------------- Frobenius norm per batch ----------------
__global__ __launch_bounds__(256)
void frob_kernel(const float* __restrict__ Cm, float* __restrict__ nrm)
{
    int b = blockIdx.x;
    const float* p = Cm + (long)b * ND * ND;
    float s = 0.f;
    for (int i = threadIdx.x; i < ND * ND; i += 256) { float v = p[i]; s += v * v; }
    __shared__ float red[256];
    red[threadIdx.x] = s; __syncthreads();
    for (int off = 128; off > 0; off >>= 1) {
        if (threadIdx.x < off) red[threadIdx.x] += red[threadIdx.x + off];
        __syncthreads();
    }
    if (threadIdx.x == 0) nrm[b] = sqrtf(red[0]);
}

// ---------------- Y0 = C/normC (in place), Z0 = I ----------------
__global__ __launch_bounds__(256)
void init_kernel(float* __restrict__ Y, float* __restrict__ Z, const float* __restrict__ nrm)
{
    const int total = BATCH * ND * ND;
    for (int idx = blockIdx.x * 256 + threadIdx.x; idx < total; idx += gridDim.x * 256) {
        int b = idx / (ND * ND);
        int rem = idx - b * (ND * ND);
        int r = rem / ND, c = rem - r * ND;
        Y[idx] = Y[idx] / nrm[b];
        Z[idx] = (r == c) ? 1.f : 0.f;
    }
}

// ---------------- block reduction over 768 threads ----------------
__device__ __forceinline__ float bred768(float v, float* red12, int t)
{
#pragma unroll
    for (int off = 32; off > 0; off >>= 1) v += __shfl_down(v, off);
    if ((t & 63) == 0) red12[t >> 6] = v;
    __syncthreads();
    float r = 0.f;
#pragma unroll
    for (int i = 0; i < 12; i++) r += red12[i];
    __syncthreads();
    return r;
}

// ---------------- Blocked Householder tridiagonalization: panel kernel ----------
// Matvec: thread = (column-quad g, row-slice s); dwordx4 loads, unroll-8 ->
// ~4x bytes-in-flight vs scalar 2-way split (the panel is MLP-bound at 64 CUs).
__global__ __launch_bounds__(768)
void tridiag_panel(float* __restrict__ Gall, float* __restrict__ dA,
                   float* __restrict__ eA, float* __restrict__ tauA,
                   float* __restrict__ Wgall, int k0)
{
    int b = blockIdx.x;
    float* A = Gall + (long)b * ND * ND;
    float* Wg = Wgall + (long)b * (PNB * ND);
    float* d = dA + b * ND; float* e = eA + b * ND; float* tau = tauA + b * ND;
    const int t = threadIdx.x;
    const int h = (t >= ND) ? 1 : 0;
    const int c = t - h * ND;            // 0..383
    const int g = t % 96;                // column quad (4 cols)
    const int s = t / 96;                // row slice 0..7
    __shared__ float u_s[ND];
    __shared__ float pp4s[8][392];
    __shared__ float ukv[PNB], wkv[PNB], al[PNB], be[PNB];
    __shared__ float red12[12];
    __shared__ float s_tau;

    const int jcnt = min(PNB, ND - 2 - k0);

    for (int j = 0; j < jcnt; j++) {
        const int k = k0 + j;
        const int m = ND - 1 - k;
        if (t < j) { ukv[t] = A[(long)(k0 + t) * ND + k]; wkv[t] = Wg[t * ND + k]; }
        __syncthreads();
        float x = 0.f;
        if (!h && c < m) {
            x = A[(long)k * ND + (k + 1) + c];
            for (int l = 0; l < j; l++) {
                x -= ukv[l] * Wg[l * ND + (k + 1) + c]
                   + wkv[l] * A[(long)(k0 + l) * ND + (k + 1) + c];
            }
            u_s[c] = x;
        }
        float sigma = bred768(x * x, red12, t);
        if (t == 0) {
            float v0 = u_s[0];
            float normx = sqrtf(sigma);
            float alpha = (v0 >= 0.f) ? -normx : normx;
            float denom = sigma - alpha * v0;
            float tk = (denom > 1e-30f) ? 1.f / denom : 0.f;
            s_tau = tk;
            float diag = A[(long)k * ND + k];
            for (int l = 0; l < j; l++) diag -= 2.f * ukv[l] * wkv[l];
            e[k] = alpha; tau[k] = tk; d[k] = diag;
            u_s[0] = v0 - alpha;
        }
        __syncthreads();
        const float tk = s_tau;

        // ---- matvec over the clean trailing block: dwordx4, 8-way row split ----
        // aligned column window [kk4, 384); <=3 garbage front columns discarded.
        const int kk4 = (k + 1) & ~3;
        const int off = (k + 1) - kk4;
        const int ncol4 = 96 - (kk4 >> 2);
        if (g < ncol4) {
            const int ri0 = (m * s) >> 3;
            const int ri1 = (m * (s + 1)) >> 3;
            const float* base = A + (long)(k + 1) * ND + kk4 + 4 * g;
            floatx4 p4 = (floatx4){0.f, 0.f, 0.f, 0.f};
            int i = ri0;
            for (; i + 8 <= ri1; i += 8) {
                floatx4 a0 = *(const floatx4*)&base[(long)(i    ) * ND];
                floatx4 a1 = *(const floatx4*)&base[(long)(i + 1) * ND];
                floatx4 a2 = *(const floatx4*)&base[(long)(i + 2) * ND];
                floatx4 a3 = *(const floatx4*)&base[(long)(i + 3) * ND];
                floatx4 a4 = *(const floatx4*)&base[(long)(i + 4) * ND];
                floatx4 a5 = *(const floatx4*)&base[(long)(i + 5) * ND];
                floatx4 a6 = *(const floatx4*)&base[(long)(i + 6) * ND];
                floatx4 a7 = *(const floatx4*)&base[(long)(i + 7) * ND];
                p4 += a0 * u_s[i]     + a1 * u_s[i + 1] + a2 * u_s[i + 2] + a3 * u_s[i + 3]
                    + a4 * u_s[i + 4] + a5 * u_s[i + 5] + a6 * u_s[i + 6] + a7 * u_s[i + 7];
            }
            for (; i < ri1; i++) {
                floatx4 a0 = *(const floatx4*)&base[(long)i * ND];
                p4 += a0 * u_s[i];
            }
            *(floatx4*)&pp4s[s][4 * g] = p4;
        }
        // wave-parallel dots: al[l] = w_l . u, be[l] = u_l . u
        {
            int wv = t >> 6, ln = t & 63;
            for (int l = wv; l < j; l += 12) {
                float sa = 0.f, sb = 0.f;
                const float* wrow = Wg + l * ND + (k + 1);
                const float* urow = A + (long)(k0 + l) * ND + (k + 1);
                for (int i = ln; i < m; i += 64) { sa += wrow[i] * u_s[i]; sb += urow[i] * u_s[i]; }
#pragma unroll
                for (int off2 = 32; off2 > 0; off2 >>= 1) {
                    sa += __shfl_down(sa, off2); sb += __shfl_down(sb, off2);
                }
                if (ln == 0) { al[l] = sa; be[l] = sb; }
            }
        }
        __syncthreads();
        float contrib = 0.f, pc = 0.f;
        if (!h && c < m) {
            int ca = c + off;
            pc = pp4s[0][ca] + pp4s[1][ca] + pp4s[2][ca] + pp4s[3][ca]
               + pp4s[4][ca] + pp4s[5][ca] + pp4s[6][ca] + pp4s[7][ca];
            for (int l = 0; l < j; l++) {
                pc -= al[l] * A[(long)(k0 + l) * ND + (k + 1) + c]
                    + be[l] * Wg[l * ND + (k + 1) + c];
            }
            pc *= tk;
            contrib = u_s[c] * pc;
        }
        float dotup = bred768(contrib, red12, t);
        float sc = 0.5f * tk * dotup;
        if (!h && c < m) {
            float w = pc - sc * u_s[c];
            Wg[j * ND + (k + 1) + c] = w;
            A[(long)k * ND + (k + 1) + c] = u_s[c];
        }
        __syncthreads();
    }
    if (k0 + PNB >= ND - 2 && t == 0) {
        float d0 = A[(long)(ND - 2) * ND + (ND - 2)];
        float e0 = A[(long)(ND - 2) * ND + (ND - 1)];
        float d1 = A[(long)(ND - 1) * ND + (ND - 1)];
        for (int l = 0; l < jcnt; l++) {
            float u0 = A[(long)(k0 + l) * ND + (ND - 2)];
            float u1 = A[(long)(k0 + l) * ND + (ND - 1)];
            float w0 = Wg[l * ND + (ND - 2)];
            float w1 = Wg[l * ND + (ND - 1)];
            d0 -= 2.f * u0 * w0;
            e0 -= u0 * w1 + w0 * u1;
            d1 -= 2.f * u1 * w1;
        }
        d[ND - 2] = d0; d[ND - 1] = d1; e[ND - 2] = e0;
        e[ND - 1] = 0.f; tau[ND - 2] = 0.f; tau[ND - 1] = 0.f;
    }
}

// ---------------- trailing update: A -= U W^T + W U^T (full device) ----------
__global__ __launch_bounds__(256)
void syr2k_update(float* __restrict__ Gall, const float* __restrict__ Wgall, int k0)
{
    const int k1 = k0 + PNB;
    const int tiles = (ND - k1) >> 6;
    int b = blockIdx.y;
    int ti = blockIdx.x / tiles, tj = blockIdx.x % tiles;
    int i0 = k1 + ti * 64, c0 = k1 + tj * 64;
    float* A = Gall + (long)b * ND * ND;
    const float* Wg = Wgall + (long)b * (PNB * ND);

    __shared__ float Us[PNB][65], Ws[PNB][65], Uc[PNB][65], Wc[PNB][65];
    int t = threadIdx.x;
    for (int q = t; q < PNB * 16; q += 256) {
        int l = q >> 4, c4 = (q & 15) * 4;
        *(float4*)&Us[l][c4] = *(const float4*)&A[(long)(k0 + l) * ND + i0 + c4];
        *(float4*)&Ws[l][c4] = *(const float4*)&Wg[l * ND + i0 + c4];
        *(float4*)&Uc[l][c4] = *(const float4*)&A[(long)(k0 + l) * ND + c0 + c4];
        *(float4*)&Wc[l][c4] = *(const float4*)&Wg[l * ND + c0 + c4];
    }
    __syncthreads();
    int tr = t >> 4, tc = t & 15;
    float acc[4][4];
#pragma unroll
    for (int a = 0; a < 4; a++)
#pragma unroll
        for (int q = 0; q < 4; q++) acc[a][q] = 0.f;
    for (int l = 0; l < PNB; l++) {
        float ua[4], wa[4], ub[4], wb[4];
#pragma unroll
        for (int a = 0; a < 4; a++) {
            ua[a] = Us[l][tr * 4 + a]; wa[a] = Ws[l][tr * 4 + a];
            ub[a] = Uc[l][tc * 4 + a]; wb[a] = Wc[l][tc * 4 + a];
        }
#pragma unroll
        for (int a = 0; a < 4; a++)
#pragma unroll
            for (int q = 0; q < 4; q++) acc[a][q] += ua[a] * wb[q] + wa[a] * ub[q];
    }
#pragma unroll
    for (int a = 0; a < 4; a++) {
        float* crow = &A[(long)(i0 + tr * 4 + a) * ND + c0 + tc * 4];
        float4 old = *(const float4*)crow;
        old.x -= acc[a][0]; old.y -= acc[a][1]; old.z -= acc[a][2]; old.w -= acc[a][3];
        *(float4*)crow = old;
    }
}

// ---------------- Sturm bisection: top-24 eigenvalues ----------------
__global__ __launch_bounds__(64)
void eigvals_kernel(const float* __restrict__ dA, const float* __restrict__ eA,
                    float* __restrict__ lamA)
{
    int b = blockIdx.x, t = threadIdx.x;   // 64 threads
    __shared__ float2 de[ND];
    __shared__ float d_s[ND], ea[ND], red[64];
    for (int i = t; i < ND; i += 64) {
        float dv = dA[b * ND + i];
        float ev = eA[b * ND + i];
        float ep = (i > 0) ? eA[b * ND + i - 1] : 0.f;
        d_s[i] = dv; ea[i] = fabsf(ev);
        de[i] = make_float2(dv, ep * ep + 1e-38f);
    }
    __syncthreads();
    float lo = 1e30f, hi = -1e30f;
    for (int i = t; i < ND; i += 64) {
        float r = ea[i] + ((i > 0) ? ea[i - 1] : 0.f);
        lo = fminf(lo, d_s[i] - r); hi = fmaxf(hi, d_s[i] + r);
    }
    red[t] = lo; __syncthreads();
    for (int off = 32; off > 0; off >>= 1) {
        if (t < off) red[t] = fminf(red[t], red[t + off]);
        __syncthreads();
    }
    lo = red[0]; __syncthreads();
    red[t] = hi; __syncthreads();
    for (int off = 32; off > 0; off >>= 1) {
        if (t < off) red[t] = fmaxf(red[t], red[t + off]);
        __syncthreads();
    }
    hi = red[0];
    if (t < RK) {
        int idx = ND - 1 - t;          // ascending index (t=0 -> largest)
        float a = lo, c = hi;
        for (int it = 0; it < 42; it++) {
            float mid = 0.5f * (a + c);
            int cnt = 0;
            float qinv = 0.f;
            for (int i = 0; i < ND; i += 8) {
                float2 v0 = de[i    ], v1 = de[i + 1], v2 = de[i + 2], v3 = de[i + 3];
                float2 v4 = de[i + 4], v5 = de[i + 5], v6 = de[i + 6], v7 = de[i + 7];
                float q;
                q = (v0.x - mid) - v0.y * qinv; cnt += (q < 0.f); qinv = __builtin_amdgcn_rcpf(q);
                q = (v1.x - mid) - v1.y * qinv; cnt += (q < 0.f); qinv = __builtin_amdgcn_rcpf(q);
                q = (v2.x - mid) - v2.y * qinv; cnt += (q < 0.f); qinv = __builtin_amdgcn_rcpf(q);
                q = (v3.x - mid) - v3.y * qinv; cnt += (q < 0.f); qinv = __builtin_amdgcn_rcpf(q);
                q = (v4.x - mid) - v4.y * qinv; cnt += (q < 0.f); qinv = __builtin_amdgcn_rcpf(q);
                q = (v5.x - mid) - v5.y * qinv; cnt += (q < 0.f); qinv = __builtin_amdgcn_rcpf(q);
                q = (v6.x - mid) - v6.y * qinv; cnt += (q < 0.f); qinv = __builtin_amdgcn_rcpf(q);
                q = (v7.x - mid) - v7.y * qinv; cnt += (q < 0.f); qinv = __builtin_amdgcn_rcpf(q);
            }
            if (cnt > idx) c = mid; else a = mid;
        }
        lamA[b * RK + t] = 0.5f * (a + c);
    }
}

// ---------------- tridiagonal inverse iteration (pivoted LU) ----------------
__global__ __launch_bounds__(64)
void invit_kernel(const float* __restrict__ dA, const float* __restrict__ eA,
                  const float* __restrict__ lamA, float* __restrict__ scr)
{
    int b = blockIdx.x, t = threadIdx.x;
    __shared__ float d[ND], e[ND];
    for (int i = t; i < ND; i += 64) { d[i] = dA[b * ND + i]; e[i] = eA[b * ND + i]; }
    __syncthreads();
    if (t >= RK) return;
    const int s = b * RK + t;
    float* ua = scr;
    float* ub = scr + (long)ND * SSTR;
    float* uc = scr + 2L * ND * SSTR;
    float* ul = scr + 3L * ND * SSTR;
    float* up = scr + 4L * ND * SSTR;
    float* y  = scr + 5L * ND * SSTR;
    float lam = lamA[s];
    float ai = d[0] - lam;
    float bc = e[0];
    for (int i = 0; i < ND - 1; i++) {
        float sub = e[i];
        float dn = d[i + 1] - lam;
        float en = (i + 1 < ND - 1) ? e[i + 1] : 0.f;
        long o = (long)i * SSTR + s;
        if (fabsf(ai) >= fabsf(sub)) {
            float aa = (ai == 0.f) ? 1e-20f : ai;
            float mlt = sub / aa;
            ua[o] = aa; ub[o] = bc; uc[o] = 0.f; ul[o] = mlt; up[o] = 0.f;
            ai = dn - mlt * bc;
            bc = en;
        } else {
            float mlt = ai / sub;
            ua[o] = sub; ub[o] = dn; uc[o] = en; ul[o] = mlt; up[o] = 1.f;
            ai = bc - mlt * dn;
            bc = -mlt * en;
        }
    }
    { long o = (long)(ND - 1) * SSTR + s; ua[o] = (ai == 0.f) ? 1e-20f : ai; ub[o] = 0.f; uc[o] = 0.f; }

    for (int pass = 0; pass < 2; pass++) {
        if (pass == 0) {
            for (int i = 0; i < ND; i++) {
                unsigned h = ((unsigned)i * 1103515245u) ^ ((unsigned)s * 747796405u);
                h *= 2654435769u; h ^= h >> 16;
                y[(long)i * SSTR + s] = ((float)(h & 0xFFFFu) * (1.f / 65536.f)) - 0.5f;
            }
        }
        for (int i = 0; i < ND - 1; i++) {
            long o = (long)i * SSTR + s, o1 = o + SSTR;
            float yi = y[o], y1 = y[o1];
            if (up[o] == 0.f) { y[o1] = y1 - ul[o] * yi; }
            else { y[o] = y1; y[o1] = yi - ul[o] * y1; }
        }
        {
            long oN = (long)(ND - 1) * SSTR + s;
            float xN = y[oN] / ua[oN]; y[oN] = xN;
            long o = oN - SSTR;
            float x1 = xN, x2 = 0.f;
            float xm = (y[o] - ub[o] * x1) / ua[o]; y[o] = xm; x2 = x1; x1 = xm;
            for (int i = ND - 3; i >= 0; i--) {
                o -= SSTR;
                float xi = (y[o] - ub[o] * x1 - uc[o] * x2) / ua[o];
                y[o] = xi; x2 = x1; x1 = xi;
            }
        }
        float nn = 0.f;
        for (int i = 0; i < ND; i++) { float v = y[(long)i * SSTR + s]; nn += v * v; }
        float inv = (nn > 0.f) ? 1.f / sqrtf(nn) : 0.f;
        for (int i = 0; i < ND; i++) y[(long)i * SSTR + s] *= inv;
    }
}

// ---------------- MGS + Householder back-transform (one WG per batch) ----------------
__device__ __forceinline__ float blockSum384(float v, float* red6, int t)
{
#pragma unroll
    for (int off = 32; off > 0; off >>= 1) v += __shfl_down(v, off);
    __syncthreads();
    if ((t & 63) == 0) red6[t >> 6] = v;
    __syncthreads();
    return red6[0] + red6[1] + red6[2] + red6[3] + red6[4] + red6[5];
}

__global__ __launch_bounds__(384)
void orthbt_kernel(const float* __restrict__ xx, const float* __restrict__ Gall,
                   const float* __restrict__ tauA, float* __restrict__ Qout)
{
    int b = blockIdx.x, t = threadIdx.x;   // 384 threads
    __shared__ float Y[ND][RK + 1];
    __shared__ float u[ND];
    __shared__ float red[ND];
    __shared__ float red6[8];
    __shared__ float sarr[RK];

    for (int j = 0; j < RK; j++) Y[t][j] = xx[(long)t * SSTR + b * RK + j];
    __syncthreads();

    for (int j = 0; j < RK; j++) {
        float nv = blockSum384(Y[t][j] * Y[t][j], red6, t);
        float inv = (nv > 1e-30f) ? 1.f / sqrtf(nv) : 0.f;
        Y[t][j] *= inv;
        for (int l = j + 1; l < RK; l++) {
            float dt = blockSum384(Y[t][j] * Y[t][l], red6, t);
            Y[t][l] -= dt * Y[t][j];
        }
    }
    __syncthreads();

    const float* A = Gall + (long)b * ND * ND;
    const float* tau = tauA + b * ND;
    const int col = t % RK;       // 384 = 16*24
    const int sl = t / RK;
    for (int k = ND - 3; k >= 0; k--) {
        int m = ND - 1 - k;
        for (int i = t; i < m; i += 384) u[i] = A[(long)k * ND + (k + 1 + i)];
        float tk = tau[k];
        __syncthreads();
        float p = 0.f;
        for (int i = sl; i < m; i += 16) p += u[i] * Y[k + 1 + i][col];
        red[col * 16 + sl] = p; __syncthreads();
        if (sl == 0) {
            float ssum = 0.f;
            for (int q = 0; q < 16; q++) ssum += red[col * 16 + q];
            sarr[col] = tk * ssum;
        }
        __syncthreads();
        float sv = sarr[col];
        for (int i = sl; i < m; i += 16) Y[k + 1 + i][col] -= u[i] * sv;
        __syncthreads();
    }
    for (int l = t; l < ND * RK; l += 384) {
        int i = l / RK, j = l - i * RK;
        Qout[(long)b * ND * RK + l] = Y[i][j];
    }
}

// ---------------- Sp = X_w @ Q ----------------
__global__ __launch_bounds__(256)
void proj_kernel(const float* __restrict__ Xw, const float* __restrict__ Qall,
                 float* __restrict__ P)
{
    int b = blockIdx.y;
    int r0 = blockIdx.x * 256;
    __shared__ float Qs[ND][RK + 1];
    const float* Q = Qall + (long)b * ND * RK;
    for (int l = threadIdx.x; l < ND * RK; l += 256) {
        int i = l / RK, j = l - i * RK;
        Qs[i][j] = Q[l];
    }
    __syncthreads();
    int r = r0 + threadIdx.x;
    const float* X = Xw + (long)b * NR * ND + (long)r * ND;
    float acc[RK];
#pragma unroll
    for (int j = 0; j < RK; j++) acc[j] = 0.f;
    for (int k = 0; k < ND; k++) {
        float xv = X[k];
#pragma unroll
        for (int j = 0; j < RK; j++) acc[j] += xv * Qs[k][j];
    }
    float* Pr = P + (long)b * NR * RK + (long)r * RK;
#pragma unroll
    for (int j = 0; j < RK; j++) Pr[j] = acc[j];
}

// ---------------- M = Sp^T Tp ; R = polar(M) via Newton-Schulz ; write R - I ----------------
__global__ __launch_bounds__(256)
void polar_kernel(const float* __restrict__ Sp, const float* __restrict__ Tp,
                  float* __restrict__ RmI)
{
    int b = blockIdx.x, t = threadIdx.x;
    __shared__ float Sb[128][RK + 1], Tb[128][RK + 1];
    __shared__ float Xm[RK][RK + 1], Bm[RK][RK + 1], Mm[RK][RK + 1];
    __shared__ float red[256];

    float accM[3] = {0.f, 0.f, 0.f};
    for (int c = 0; c < 4; c++) {
        for (int l = t; l < 128 * RK; l += 256) {
            int row = l / RK, colj = l - row * RK;
            Sb[row][colj] = Sp[(long)b * NR * RK + (long)(c * 128 + row) * RK + colj];
            Tb[row][colj] = Tp[(long)b * NR * RK + (long)(c * 128 + row) * RK + colj];
        }
        __syncthreads();
        for (int q = 0; q < 3; q++) {
            int e = t + q * 256;
            if (e < RK * RK) {
                int r = e / RK, s2 = e - r * RK;
                float a = 0.f;
                for (int n = 0; n < 128; n++) a += Sb[n][r] * Tb[n][s2];
                accM[q] += a;
            }
        }
        __syncthreads();
    }
    float ss = 0.f;
    for (int q = 0; q < 3; q++) {
        int e = t + q * 256;
        if (e < RK * RK) {
            int r = e / RK, s2 = e - r * RK;
            Mm[r][s2] = accM[q];
            ss += accM[q] * accM[q];
        }
    }
    red[t] = ss; __syncthreads();
    for (int off = 128; off > 0; off >>= 1) {
        if (t < off) red[t] += red[t + off];
        __syncthreads();
    }
    float fro = sqrtf(red[0]);
    float inv = (fro > 1e-30f) ? 1.f / fro : 0.f;
    for (int q = 0; q < 3; q++) {
        int e = t + q * 256;
        if (e < RK * RK) { int r = e / RK, s2 = e - r * RK; Xm[r][s2] = Mm[r][s2] * inv; }
    }
    __syncthreads();
    for (int it = 0; it < POLAR_ITERS; it++) {
        for (int q = 0; q < 3; q++) {
            int e = t + q * 256;
            if (e < RK * RK) {
                int r = e / RK, s2 = e - r * RK;
                float a = 0.f;
                for (int k = 0; k < RK; k++) a += Xm[k][r] * Xm[k][s2];
                Bm[r][s2] = a;
            }
        }
        __syncthreads();
        for (int q = 0; q < 3; q++) {
            int e = t + q * 256;
            if (e < RK * RK) {
                int r = e / RK, s2 = e - r * RK;
                float a = 0.f;
                for (int k = 0; k < RK; k++) a += Xm[r][k] * Bm[k][s2];
                Mm[r][s2] = 1.5f * Xm[r][s2] - 0.5f * a;
            }
        }
        __syncthreads();
        for (int q = 0; q < 3; q++) {
            int e = t + q * 256;
            if (e < RK * RK) { int r = e / RK, s2 = e - r * RK; Xm[r][s2] = Mm[r][s2]; }
        }
        __syncthreads();
    }
    for (int q = 0; q < 3; q++) {
        int e = t + q * 256;
        if (e < RK * RK) {
            int r = e / RK, s2 = e - r * RK;
            RmI[(long)b * RK * RK + e] = Xm[r][s2] - ((r == s2) ? 1.f : 0.f);
        }
    }
}

// ---------------- aligned = S_w + Sp (R-I) Q^T  (writes d_out) ----------------
__global__ __launch_bounds__(256)
void align_kernel(const float* __restrict__ Sw, const float* __restrict__ Sp,
                  const float* __restrict__ RmI, const float* __restrict__ Qall,
                  float* __restrict__ out)
{
    int b = blockIdx.y;
    int r0 = blockIdx.x * 64;
    int t = threadIdx.x;
    __shared__ float Qs[ND][RK + 1];
    __shared__ float Rm[RK][RK + 1];
    __shared__ float Ss[64][RK + 1];
    __shared__ float W[64][RK + 1];

    for (int l = t; l < ND * RK; l += 256) {
        int i = l / RK, j = l - i * RK;
        Qs[i][j] = Qall[(long)b * ND * RK + l];
    }
    for (int l = t; l < RK * RK; l += 256) {
        int i = l / RK, j = l - i * RK;
        Rm[i][j] = RmI[(long)b * RK * RK + l];
    }
    for (int l = t; l < 64 * RK; l += 256) {
        int i = l / RK, j = l - i * RK;
        Ss[i][j] = Sp[(long)b * NR * RK + (long)(r0 + i) * RK + j];
    }
    __syncthreads();
    for (int l = t; l < 64 * RK; l += 256) {
        int r = l / RK, j = l - r * RK;
        float a = 0.f;
        for (int k = 0; k < RK; k++) a += Ss[r][k] * Rm[k][j];
        W[r][j] = a;
    }
    __syncthreads();
    for (int r = 0; r < 64; r++) {
        for (int c = t; c < ND; c += 256) {
            float a = Sw[(long)b * NR * ND + (long)(r0 + r) * ND + c];
            float s2 = 0.f;
#pragma unroll
            for (int j = 0; j < RK; j++) s2 += W[r][j] * Qs[c][j];
            out[(long)b * NR * ND + (long)(r0 + r) * ND + c] = a + s2;
        }
    }
}

// ---------------- mean cosine ----------------
__global__ __launch_bounds__(256)
void cos_kernel(const float* __restrict__ out, const float* __restrict__ tgt,
                float* __restrict__ acc)
{
    int row = blockIdx.x * 4 + (threadIdx.x >> 6);
    int lane = threadIdx.x & 63;
    const float* a = out + (long)row * ND;
    const float* tg = tgt + (long)row * ND;
    float sd = 0.f, sa = 0.f, st = 0.f;
    for (int i = lane; i < ND; i += 64) {
        float av = a[i], tv = tg[i];
        sd += av * tv; sa += av * av; st += tv * tv;
    }
#pragma unroll
    for (int off = 32; off > 0; off >>= 1) {
        sd += __shfl_down(sd, off); sa += __shfl_down(sa, off); st += __shfl_down(st, off);
    }
    __shared__ float part[4];
    if (lane == 0) part[threadIdx.x >> 6] = sd / (sqrtf(sa) * sqrtf(st) + 1e-8f);
    __syncthreads();
    if (threadIdx.x == 0) atomicAdd(acc, part[0] + part[1] + part[2] + part[3]);
}

__global__ void finalize_kernel(const float* __restrict__ acc, float* __restrict__ out)
{
    out[0] = acc[0] / 32768.0f;
}

// ---------------- host ----------------
static inline void launch_gemm(int TA, const float* A, const float* Bm, float* C,
                               int M, int N, int K, long sA, long sB, long sC,
                               int lda, int ldb, int ldc, int mode,
                               const float* scale, hipStream_t stream)
{
    dim3 grid((M / 128) * (N / 128), BATCH);
    if (TA)
        gemm_kernel<1><<<grid, dim3(256), 0, stream>>>(A, Bm, C, M, N, K, sA, sB, sC, lda, ldb, ldc, mode, scale);
    else
        gemm_kernel<0><<<grid, dim3(256), 0, stream>>>(A, Bm, C, M, N, K, sA, sB, sC, lda, ldb, ldc, mode, scale);
}

extern "C" void kernel_launch(void* const* d_in, const int* in_sizes, int n_in,
                              void* d_out, int out_size, void* d_ws, size_t ws_size,
                              hipStream_t stream)
{
    const float* src = (const float*)d_in[0];
    const float* tgt = (const float*)d_in[1];
    float* out = (float*)d_out;
    float* ws = (float*)d_ws;

    float* A0 = ws;
    float* A1 = ws + 1 * SZC;
    float* A2 = ws + 2 * SZC;
    float* A3 = ws + 3 * SZC;
    float* A4 = ws + 4 * SZC;
    float* S5 = ws + 5 * SZC;
    float* nrm_s = S5;
    float* nrm_t = S5 + 64;
    float* dd = S5 + 128;
    float* ee = dd + BATCH * ND;
    float* tt = ee + BATCH * ND;
    float* lam = tt + BATCH * ND;
    float* accp = lam + BATCH * RK;

    float* Tm = out;                 // transient NS "T" buffer lives in d_out
    float* SW = A0;                  // 512x384 per batch (spans A0..A1)
    float* TW = A0 + (long)BATCH * NR * ND;
    float* G  = A3;
    float* scr = A4;                                   // 6 * 384 * 1536
    float* Qp  = A4 + 6L * ND * SSTR;
    float* Spp = Qp + (long)BATCH * ND * RK;
    float* Tpp = Spp + (long)BATCH * NR * RK;
    float* Rp  = Tpp + (long)BATCH * NR * RK;
    float* Wg  = Rp + (long)BATCH * RK * RK;           // PNB*ND per batch
    float* yarr = scr + 5L * ND * SSTR;

    const long sXin = (long)NR * ND;     // 196608
    const long sSq  = (long)ND * ND;     // 147456

    // ---- phase S: covariance + Newton-Schulz inverse sqrt ----
    launch_gemm(1, src, src, A0, ND, ND, NR, sXin, sXin, sSq, ND, ND, ND, MODE_COV, nullptr, stream);
    frob_kernel<<<BATCH, 256, 0, stream>>>(A0, nrm_s);
    init_kernel<<<dim3(4096), 256, 0, stream>>>(A0, A2, nrm_s);
    {
        float* Y = A0; float* Yo = A1; float* Z = A2; float* Zo = A3;
        for (int it = 0; it < NSI; it++) {
            launch_gemm(0, Z, Y, Tm, ND, ND, ND, sSq, sSq, sSq, ND, ND, ND, MODE_NST, nullptr, stream);
            launch_gemm(0, Y, Tm, Yo, ND, ND, ND, sSq, sSq, sSq, ND, ND, ND, MODE_PLAIN, nullptr, stream);
            launch_gemm(0, Tm, Z, Zo, ND, ND, ND, sSq, sSq, sSq, ND, ND, ND, MODE_PLAIN, nullptr, stream);
            float* tmp = Y; Y = Yo; Yo = tmp;
            tmp = Z; Z = Zo; Zo = tmp;
        }
        // Z_s ends in A3
    }
    // ---- phase T ----
    launch_gemm(1, tgt, tgt, A0, ND, ND, NR, sXin, sXin, sSq, ND, ND, ND, MODE_COV, nullptr, stream);
    frob_kernel<<<BATCH, 256, 0, stream>>>(A0, nrm_t);
    init_kernel<<<dim3(4096), 256, 0, stream>>>(A0, A2, nrm_t);
    {
        float* Y = A0; float* Yo = A1; float* Z = A2; float* Zo = A4;
        for (int it = 0; it < NSI; it++) {
            launch_gemm(0, Z, Y, Tm, ND, ND, ND, sSq, sSq, sSq, ND, ND, ND, MODE_NST, nullptr, stream);
            launch_gemm(0, Y, Tm, Yo, ND, ND, ND, sSq, sSq, sSq, ND, ND, ND, MODE_PLAIN, nullptr, stream);
            launch_gemm(0, Tm, Z, Zo, ND, ND, ND, sSq, sSq, sSq, ND, ND, ND, MODE_PLAIN, nullptr, stream);
            float* tmp = Y; Y = Yo; Yo = tmp;
            tmp = Z; Z = Zo; Zo = tmp;
        }
        // Z_t ends in A4
    }
    // ---- whiten ----
    launch_gemm(0, src, A3, SW, NR, ND, ND, sXin, sSq, sXin, ND, ND, ND, MODE_SCALE, nrm_s, stream);
    launch_gemm(0, tgt, A4, TW, NR, ND, ND, sXin, sSq, sXin, ND, ND, ND, MODE_SCALE, nrm_t, stream);
    // ---- G = S_w^T S_w + T_w^T T_w ----
    launch_gemm(1, SW, SW, G, ND, ND, NR, sXin, sXin, sSq, ND, ND, ND, MODE_PLAIN, nullptr, stream);
    launch_gemm(1, TW, TW, G, ND, ND, NR, sXin, sXin, sSq, ND, ND, ND, MODE_ACC, nullptr, stream);
    // ---- blocked tridiagonalization: panels + full-device trailing updates ----
    for (int p = 0; p < ND / PNB; p++) {
        tridiag_panel<<<BATCH, 768, 0, stream>>>(G, dd, ee, tt, Wg, p * PNB);
        int k1 = (p + 1) * PNB;
        if (k1 < ND - 2) {
            int tiles = (ND - k1) / 64;
            syr2k_update<<<dim3(tiles * tiles, BATCH), 256, 0, stream>>>(G, Wg, p * PNB);
        }
    }
    eigvals_kernel<<<BATCH, 64, 0, stream>>>(dd, ee, lam);
    invit_kernel<<<BATCH, 64, 0, stream>>>(dd, ee, lam, scr);
    orthbt_kernel<<<BATCH, 384, 0, stream>>>(yarr, G, tt, Qp);
    // ---- projections, Procrustes, output ----
    proj_kernel<<<dim3(2, BATCH), 256, 0, stream>>>(SW, Qp, Spp);
    proj_kernel<<<dim3(2, BATCH), 256, 0, stream>>>(TW, Qp, Tpp);
    polar_kernel<<<BATCH, 256, 0, stream>>>(Spp, Tpp, Rp);
    align_kernel<<<dim3(8, BATCH), 256, 0, stream>>>(SW, Spp, Rp, Qp, out);
    hipMemsetAsync((void*)accp, 0, 4, stream);
    cos_kernel<<<dim3(8192), 256, 0, stream>>>(out, tgt, accp);
    finalize_kernel<<<1, 1, 0, stream>>>(accp, out + (long)BATCH * NR * ND);
    (void)in_sizes; (void)n_in; (void)out_size; (void)ws_size;
}